// Round 9
// baseline (254.611 us; speedup 1.0000x reference)
//
#include <hip/hip_runtime.h>
#include <math.h>

constexpr int NN  = 50000;   // nodes (< 65536 -> csr fits in ushort)
constexpr int NP  = 50048;   // padded rows (multiple of 128)
constexpr int NE  = 800000;  // edges
constexpr int NEP = 200000;  // pred edges

// CSR-build binning
constexpr int NBKT  = 256;   // bins; bin = dst >> 8
constexpr int CAP   = 4096;  // per-bin capacity (mean 3125, ~17 sigma slack)
constexpr int CHUNK = 1024;  // edges per bucket workgroup

// fused front-end block ranges (x2h removed — GEMM0 reads fp32 directly)
constexpr int BKB = (NE + CHUNK - 1) / CHUNK;          // 782 bucket blocks
constexpr int W0B = 128 * 128 / 256;                   // 64
constexpr int W1B = 128 * 64 / 256;                    // 32
constexpr int W2B = 64 * 32 / 256;                     // 8
constexpr int FRONT_BLOCKS = BKB + W0B + W1B + W2B;

typedef _Float16 half4_t __attribute__((ext_vector_type(4)));
typedef _Float16 half8_t __attribute__((ext_vector_type(8)));
typedef float    float4_t __attribute__((ext_vector_type(4)));

static inline int cdiv(long long a, int b) { return (int)((a + b - 1) / b); }

// ---------------- fused front end: bucket edges + W transposes ----------------
__global__ __launch_bounds__(256) void k_front(const int* __restrict__ src,
        const int* __restrict__ dst, int* __restrict__ binCnt,
        unsigned int* __restrict__ ebuf,
        const float* __restrict__ cw0, _Float16* __restrict__ WT0,
        const float* __restrict__ cw1, _Float16* __restrict__ WT1,
        const float* __restrict__ cw2, _Float16* __restrict__ WT2) {
    const int tid = threadIdx.x;
    const int bid = blockIdx.x;

    if (bid < BKB) {
        __shared__ int hist[NBKT];
        __shared__ int base[NBKT];
        __shared__ int cur[NBKT];
        const int e0 = bid * CHUNK;
        hist[tid] = 0;
        __syncthreads();
        int  s[4], bn[4], dl[4];
        bool ok[4];
#pragma unroll
        for (int j = 0; j < 4; ++j) {
            int i = e0 + j * 256 + tid;
            ok[j] = i < NE;
            if (ok[j]) {
                int d = dst[i];
                s[j]  = src[i];
                bn[j] = d >> 8;
                dl[j] = d & 255;
                atomicAdd(&hist[bn[j]], 1);
            }
        }
        __syncthreads();
        base[tid] = hist[tid] ? atomicAdd(&binCnt[tid], hist[tid]) : 0;
        cur[tid] = 0;
        __syncthreads();
#pragma unroll
        for (int j = 0; j < 4; ++j) {
            if (ok[j]) {
                int slot = base[bn[j]] + atomicAdd(&cur[bn[j]], 1);
                ebuf[bn[j] * CAP + slot] = (unsigned int)s[j] | ((unsigned int)dl[j] << 16);
            }
        }
        return;
    }
    if (bid < BKB + W0B) {
        int idx = (bid - BKB) * 256 + tid;
        int k = idx >> 7, n = idx & 127;            // K=128, N=128
        WT0[(size_t)n * 128 + k] = (_Float16)cw0[idx];
        return;
    }
    if (bid < BKB + W0B + W1B) {
        int idx = (bid - BKB - W0B) * 256 + tid;
        int k = idx >> 6, n = idx & 63;             // K=128, N=64
        WT1[(size_t)n * 128 + k] = (_Float16)cw1[idx];
        return;
    }
    {
        int idx = (bid - BKB - W0B - W1B) * 256 + tid;
        int k = idx >> 5, n = idx & 31;             // K=64, N=32
        WT2[(size_t)n * 64 + k] = (_Float16)cw2[idx];
    }
}

// ---------------- CSR build: per-bin segment + off + dis (self-scans binCnt) ----------------
__global__ __launch_bounds__(256) void k_csrbuild(const unsigned int* __restrict__ ebuf,
        const int* __restrict__ binCnt, int* __restrict__ off, float* __restrict__ dis,
        unsigned short* __restrict__ csr) {
    __shared__ int borig[NBKT];
    __shared__ int bscan[NBKT];
    __shared__ int hist[256];
    __shared__ int sh[256];
    __shared__ int cur[256];
    const int tid = threadIdx.x;
    const int bin = blockIdx.x;

    int bv = binCnt[tid];
    borig[tid] = bv;
    bscan[tid] = bv;
    __syncthreads();
    for (int d = 1; d < NBKT; d <<= 1) {
        int t = (tid >= d) ? bscan[tid - d] : 0;
        __syncthreads();
        bscan[tid] += t;
        __syncthreads();
    }
    const int cnt   = borig[bin];
    const int start = bscan[bin] - cnt;
    const unsigned int* eb = ebuf + (size_t)bin * CAP;

    hist[tid] = 0;
    __syncthreads();
    for (int i = tid; i < cnt; i += 256)
        atomicAdd(&hist[eb[i] >> 16], 1);
    __syncthreads();

    int v = hist[tid];
    sh[tid] = v;
    __syncthreads();
    for (int d = 1; d < 256; d <<= 1) {
        int t = (tid >= d) ? sh[tid - d] : 0;
        __syncthreads();
        sh[tid] += t;
        __syncthreads();
    }
    int gpos = start + sh[tid] - v;

    int node = bin * 256 + tid;
    if (node <= NN) off[node] = gpos;
    if (node < NN)  dis[node] = rsqrtf((float)v + 1.0f);
    cur[tid] = gpos;
    __syncthreads();

    for (int i = tid; i < cnt; i += 256) {
        unsigned int e = eb[i];
        int p = atomicAdd(&cur[e >> 16], 1);
        csr[p] = (unsigned short)(e & 0xFFFFu);
    }
}

// ---------------- MFMA GEMM: g = dis * (X @ WT^T); A is fp32 or fp16 ----------------
template<int K, int DOUT, int SPLIT, bool F32A>
__global__ __launch_bounds__(256) void k_gemm_mfma(const void* __restrict__ Xv,
        const _Float16* __restrict__ WT, const float* __restrict__ dis,
        _Float16* __restrict__ g, int n) {
    constexpr int CW = (DOUT >= 128) ? 2 : 1;
    constexpr int RW = 4 / CW;
    constexpr int NC = DOUT / CW;
    constexpr int NT = NC / 16;
    constexpr int KT = K / 32;
    constexpr int MT = 2;
    constexpr int BR = RW * 32;
    constexpr int SW = DOUT / SPLIT;

    const int tid  = threadIdx.x;
    const int L    = tid & 63;
    const int w    = tid >> 6;
    const int wc   = w % CW;
    const int wr   = w / CW;
    const int r0   = blockIdx.x * BR + wr * 32;
    const int c0   = wc * NC;
    const int quad = L >> 4;
    const int lm   = L & 15;

    float4_t acc[MT][NT];
#pragma unroll
    for (int mt = 0; mt < MT; ++mt)
#pragma unroll
        for (int nt = 0; nt < NT; ++nt) acc[mt][nt] = (float4_t){0.f, 0.f, 0.f, 0.f};

#pragma unroll
    for (int kt = 0; kt < KT; ++kt) {
        half8_t a[MT], b[NT];
#pragma unroll
        for (int mt = 0; mt < MT; ++mt) {
            const size_t roff = (size_t)(r0 + mt * 16 + lm) * K + kt * 32 + quad * 8;
            if (F32A) {
                const float* xr = (const float*)Xv + roff;
                float4 u = *(const float4*)xr;
                float4 v = *(const float4*)(xr + 4);
                a[mt] = (half8_t){(_Float16)u.x, (_Float16)u.y, (_Float16)u.z, (_Float16)u.w,
                                  (_Float16)v.x, (_Float16)v.y, (_Float16)v.z, (_Float16)v.w};
            } else {
                a[mt] = *(const half8_t*)((const _Float16*)Xv + roff);
            }
        }
#pragma unroll
        for (int nt = 0; nt < NT; ++nt)
            b[nt] = *(const half8_t*)(WT + (size_t)(c0 + nt * 16 + lm) * K + kt * 32 + quad * 8);
#pragma unroll
        for (int mt = 0; mt < MT; ++mt)
#pragma unroll
            for (int nt = 0; nt < NT; ++nt)
                acc[mt][nt] = __builtin_amdgcn_mfma_f32_16x16x32_f16(a[mt], b[nt], acc[mt][nt], 0, 0, 0);
    }

#pragma unroll
    for (int mt = 0; mt < MT; ++mt) {
        int rb = r0 + mt * 16 + quad * 4;
        float dv[4];
        *(float4*)dv = *(const float4*)(dis + rb);
#pragma unroll
        for (int nt = 0; nt < NT; ++nt) {
            int c     = c0 + nt * 16 + lm;
            int slice = c / SW;
            int cl    = c - slice * SW;
            _Float16* gp = g + (size_t)slice * n * SW + cl;
#pragma unroll
            for (int reg = 0; reg < 4; ++reg) {
                int r = rb + reg;
                if (r < n) gp[(size_t)r * SW] = (_Float16)(acc[mt][nt][reg] * dv[reg]);
            }
        }
    }
}

// ---------------- XCD-aligned 32-ch-slice CSR aggregation ----------------
// slice chosen from blockIdx%8 so all blocks touching a slice land on the same
// XCD pair/quad -> slice (3.2 MB) stays resident in that XCD's 4 MB L2.
// out = relu(dis[d]*(g[d]+sum g[s]) + b) as fp16 into column window of Hact.
template<int NSLICE>
__global__ __launch_bounds__(256) void k_agg32(const half4_t* __restrict__ gBase,
        const float* __restrict__ dis, const float* __restrict__ bBase,
        const int* __restrict__ off, const unsigned short* __restrict__ csr,
        half4_t* __restrict__ outBase, int stride4, int n) {
    constexpr int TPN = 8;           // 32 ch = 8 half4 lanes
    constexpr int NPB = 32;          // nodes per block
    constexpr int GPS = 8 / NSLICE;  // blockIdx%8 groups per slice
    const int bid = blockIdx.x;
    const int gg  = bid & 7;
    const int s   = gg / GPS;
    const int p   = gg % GPS;
    const int nodeBlk = (bid >> 3) * GPS + p;
    const int lane = threadIdx.x & 7;
    const int node = nodeBlk * NPB + (threadIdx.x >> 3);
    if (node >= n) return;

    const half4_t* g = gBase + (size_t)s * n * TPN;
    float dd = dis[node];
    half4_t hv = g[(size_t)node * TPN + lane];
    float ax = (float)hv.x, ay = (float)hv.y, az = (float)hv.z, aw = (float)hv.w;
    int e0 = off[node], e1 = off[node + 1];
    int e = e0;
    for (; e + 3 < e1; e += 4) {
        int s0 = csr[e], s1 = csr[e + 1], s2 = csr[e + 2], s3 = csr[e + 3];
        half4_t v0 = g[(size_t)s0 * TPN + lane];
        half4_t v1 = g[(size_t)s1 * TPN + lane];
        half4_t v2 = g[(size_t)s2 * TPN + lane];
        half4_t v3 = g[(size_t)s3 * TPN + lane];
        ax += (float)v0.x; ay += (float)v0.y; az += (float)v0.z; aw += (float)v0.w;
        ax += (float)v1.x; ay += (float)v1.y; az += (float)v1.z; aw += (float)v1.w;
        ax += (float)v2.x; ay += (float)v2.y; az += (float)v2.z; aw += (float)v2.w;
        ax += (float)v3.x; ay += (float)v3.y; az += (float)v3.z; aw += (float)v3.w;
    }
    for (; e < e1; ++e) {
        int s0 = csr[e];
        half4_t v0 = g[(size_t)s0 * TPN + lane];
        ax += (float)v0.x; ay += (float)v0.y; az += (float)v0.z; aw += (float)v0.w;
    }
    float4 bb = ((const float4*)bBase)[s * TPN + lane];
    half4_t o;
    o.x = (_Float16)fmaxf(fmaf(ax, dd, bb.x), 0.f);
    o.y = (_Float16)fmaxf(fmaf(ay, dd, bb.y), 0.f);
    o.z = (_Float16)fmaxf(fmaf(az, dd, bb.z), 0.f);
    o.w = (_Float16)fmaxf(fmaf(aw, dd, bb.w), 0.f);
    outBase[(size_t)node * stride4 + s * TPN + lane] = o;
}

// ---------------- conv2 aggregate (32ch) fused with MLP head ----------------
__global__ __launch_bounds__(256) void k_agg_mlp(const half4_t* __restrict__ g,
        const float* __restrict__ dis, const float* __restrict__ b,
        const int* __restrict__ off, const unsigned short* __restrict__ csr,
        const float* __restrict__ lw0, const float* __restrict__ lb0,
        const float* __restrict__ lw1, const float* __restrict__ lb1,
        const float* __restrict__ lw2, const float* __restrict__ lb2,
        float* __restrict__ sv, int n) {
    constexpr int TPN = 8;
    constexpr int NPB = 32;
    __shared__ float sh[NPB * 33];

    const int tid  = threadIdx.x;
    const int lane = tid % TPN;
    const int ln   = tid / TPN;
    const int node = blockIdx.x * NPB + ln;

    if (node < n) {
        float dd = dis[node];
        half4_t hv = g[(size_t)node * TPN + lane];
        float ax = (float)hv.x, ay = (float)hv.y, az = (float)hv.z, aw = (float)hv.w;
        int e0 = off[node], e1 = off[node + 1];
        int e = e0;
        for (; e + 3 < e1; e += 4) {
            int s0 = csr[e], s1 = csr[e + 1], s2 = csr[e + 2], s3 = csr[e + 3];
            half4_t v0 = g[(size_t)s0 * TPN + lane];
            half4_t v1 = g[(size_t)s1 * TPN + lane];
            half4_t v2 = g[(size_t)s2 * TPN + lane];
            half4_t v3 = g[(size_t)s3 * TPN + lane];
            ax += (float)v0.x; ay += (float)v0.y; az += (float)v0.z; aw += (float)v0.w;
            ax += (float)v1.x; ay += (float)v1.y; az += (float)v1.z; aw += (float)v1.w;
            ax += (float)v2.x; ay += (float)v2.y; az += (float)v2.z; aw += (float)v2.w;
            ax += (float)v3.x; ay += (float)v3.y; az += (float)v3.z; aw += (float)v3.w;
        }
        for (; e < e1; ++e) {
            int s0 = csr[e];
            half4_t v0 = g[(size_t)s0 * TPN + lane];
            ax += (float)v0.x; ay += (float)v0.y; az += (float)v0.z; aw += (float)v0.w;
        }
        float4 bb = ((const float4*)b)[lane];
        float* row = sh + ln * 33 + lane * 4;
        row[0] = fmaxf(fmaf(ax, dd, bb.x), 0.f);
        row[1] = fmaxf(fmaf(ay, dd, bb.y), 0.f);
        row[2] = fmaxf(fmaf(az, dd, bb.z), 0.f);
        row[3] = fmaxf(fmaf(aw, dd, bb.w), 0.f);
    }
    __syncthreads();

    if (tid < NPB) {
        int node2 = blockIdx.x * NPB + tid;
        if (node2 < n) {
            const float* v = sh + tid * 33;
            float a[16];
#pragma unroll
            for (int j = 0; j < 16; ++j) {
                float acc = lb0[j];
#pragma unroll
                for (int k = 0; k < 32; ++k) acc = fmaf(v[k], lw0[k * 16 + j], acc);
                a[j] = fmaxf(acc, 0.f);
            }
            float b8[8];
#pragma unroll
            for (int j = 0; j < 8; ++j) {
                float acc = lb1[j];
#pragma unroll
                for (int k = 0; k < 16; ++k) acc = fmaf(a[k], lw1[k * 8 + j], acc);
                b8[j] = fmaxf(acc, 0.f);
            }
            float z = lb2[0];
#pragma unroll
            for (int k = 0; k < 8; ++k) z = fmaf(b8[k], lw2[k], z);
            sv[node2] = 1.0f / (1.0f + expf(-z));
        }
    }
}

// ---------------- link prediction: 2 edges per thread ----------------
__global__ void k_pred(const float* __restrict__ s, const int* __restrict__ pe,
                       float* __restrict__ out, int ep2) {
    int i = blockIdx.x * blockDim.x + threadIdx.x;
    if (i >= ep2) return;
    int4 p = ((const int4*)pe)[i];
    float2 o;
    o.x = s[p.x] * s[p.y];
    o.y = s[p.z] * s[p.w];
    ((float2*)out)[i] = o;
}

extern "C" void kernel_launch(void* const* d_in, const int* in_sizes, int n_in,
                              void* d_out, int out_size, void* d_ws, size_t ws_size,
                              hipStream_t stream) {
    const float* x   = (const float*)d_in[0];
    const int*   ei  = (const int*)d_in[1];
    const int*   pe  = (const int*)d_in[2];
    const float* cw0 = (const float*)d_in[3];
    const float* cb0 = (const float*)d_in[4];
    const float* cw1 = (const float*)d_in[5];
    const float* cb1 = (const float*)d_in[6];
    const float* cw2 = (const float*)d_in[7];
    const float* cb2 = (const float*)d_in[8];
    const float* lw0 = (const float*)d_in[9];
    const float* lb0 = (const float*)d_in[10];
    const float* lw1 = (const float*)d_in[11];
    const float* lb1 = (const float*)d_in[12];
    const float* lw2 = (const float*)d_in[13];
    const float* lb2 = (const float*)d_in[14];

    const int* src = ei;        // edge_index[0]
    const int* dst = ei + NE;   // edge_index[1]

    // workspace layout
    char* w = (char*)d_ws;
    float*          dis  = (float*)w;           w += sizeof(float) * NN;
    _Float16*       A    = (_Float16*)w;        w += sizeof(_Float16) * (size_t)NN * 128;
    _Float16*       Hact = (_Float16*)w;        w += sizeof(_Float16) * (size_t)NP * 128;
    float*          sv   = (float*)w;           w += sizeof(float) * NN;
    _Float16*       WT0  = (_Float16*)w;        w += sizeof(_Float16) * 128 * 128;
    _Float16*       WT1  = (_Float16*)w;        w += sizeof(_Float16) * 64 * 128;
    _Float16*       WT2  = (_Float16*)w;        w += sizeof(_Float16) * 32 * 64;
    int*            off  = (int*)w;             w += sizeof(int) * (NN + 1);
    unsigned short* csr  = (unsigned short*)w;  w += sizeof(unsigned short) * NE;
    int*            binCnt = (int*)w;           w += sizeof(int) * NBKT;
    unsigned int*   ebuf = (unsigned int*)w;    w += sizeof(unsigned int) * (size_t)NBKT * CAP;

    const int T = 256;
    const int NODE_BLKS = cdiv(NN, 32);   // 1563 (32 nodes per agg block)

    // --- front end: bucket + weight transposes ---
    hipMemsetAsync(binCnt, 0, sizeof(int) * NBKT, stream);
    k_front<<<FRONT_BLOCKS, 256, 0, stream>>>(src, dst, binCnt, ebuf,
                                              cw0, WT0, cw1, WT1, cw2, WT2);

    // --- CSR build ---
    k_csrbuild<<<NBKT, 256, 0, stream>>>(ebuf, binCnt, off, dis, csr);

    // --- conv0: 128 -> 128, fp32 A; 4 slices, XCD-aligned aggregation ---
    k_gemm_mfma<128, 128, 4, true><<<NP / 64, 256, 0, stream>>>(x, WT0, dis, A, NN);
    k_agg32<4><<<cdiv(NODE_BLKS, 2) * 8, 256, 0, stream>>>((half4_t*)A, dis, cb0, off, csr,
                                                           (half4_t*)Hact, 32, NN);

    // --- conv1: 128 -> 64; 2 slices, XCD-aligned ---
    k_gemm_mfma<128, 64, 2, false><<<NP / 128, 256, 0, stream>>>(Hact, WT1, dis, A, NN);
    k_agg32<2><<<cdiv(NODE_BLKS, 4) * 8, 256, 0, stream>>>((half4_t*)A, dis, cb1, off, csr,
                                                           (half4_t*)Hact, 16, NN);

    // --- conv2: 64 -> 32; aggregate fused with MLP ---
    k_gemm_mfma<64, 32, 1, false><<<NP / 128, 256, 0, stream>>>(Hact, WT2, dis, A, NN);
    k_agg_mlp<<<cdiv(NN, 32), 256, 0, stream>>>((half4_t*)A, dis, cb2, off, csr,
                                                lw0, lb0, lw1, lb1, lw2, lb2, sv, NN);

    // --- link prediction ---
    k_pred<<<cdiv(NEP / 2, T), T, 0, stream>>>(sv, pe, (float*)d_out, NEP / 2);
}

// Round 10
// 248.488 us; speedup vs baseline: 1.0246x; 1.0246x over previous
//
#include <hip/hip_runtime.h>
#include <math.h>

constexpr int NN  = 50000;   // nodes (< 65536 -> csr fits in ushort)
constexpr int NP  = 50048;   // padded rows (multiple of 128)
constexpr int NE  = 800000;  // edges
constexpr int NEP = 200000;  // pred edges

// CSR-build binning
constexpr int NBKT  = 256;   // bins; bin = dst >> 8
constexpr int CAP   = 4096;  // per-bin capacity (mean 3125, ~17 sigma slack)
constexpr int CHUNK = 4096;  // edges per bucket workgroup (16/bin avg -> full-line appends)

// fused front-end block ranges
constexpr int BKB = (NE + CHUNK - 1) / CHUNK;          // 196 bucket blocks
constexpr int W0B = 128 * 128 / 256;                   // 64
constexpr int W1B = 128 * 64 / 256;                    // 32
constexpr int W2B = 64 * 32 / 256;                     // 8
constexpr int FRONT_BLOCKS = BKB + W0B + W1B + W2B;

constexpr int NODE_BLKS64 = (NN + 63) / 64;            // 782 blocks @ 64 nodes/block

typedef _Float16 half4_t __attribute__((ext_vector_type(4)));
typedef _Float16 half8_t __attribute__((ext_vector_type(8)));
typedef float    float4_t __attribute__((ext_vector_type(4)));

static inline int cdiv(long long a, int b) { return (int)((a + b - 1) / b); }

// ---------------- fused front end: bucket edges + W transposes ----------------
__global__ __launch_bounds__(256) void k_front(const int* __restrict__ src,
        const int* __restrict__ dst, int* __restrict__ binCnt,
        unsigned int* __restrict__ ebuf,
        const float* __restrict__ cw0, _Float16* __restrict__ WT0,
        const float* __restrict__ cw1, _Float16* __restrict__ WT1,
        const float* __restrict__ cw2, _Float16* __restrict__ WT2) {
    const int tid = threadIdx.x;
    const int bid = blockIdx.x;

    if (bid < BKB) {
        __shared__ int hist[NBKT];
        __shared__ int base[NBKT];
        __shared__ int cur[NBKT];
        constexpr int J = CHUNK / 256;   // 16 edges per thread
        const int e0 = bid * CHUNK;
        hist[tid] = 0;
        __syncthreads();
        int  s[J], bn[J], dl[J];
        bool ok[J];
#pragma unroll
        for (int j = 0; j < J; ++j) {
            int i = e0 + j * 256 + tid;
            ok[j] = i < NE;
            if (ok[j]) {
                int d = dst[i];
                s[j]  = src[i];
                bn[j] = d >> 8;
                dl[j] = d & 255;
                atomicAdd(&hist[bn[j]], 1);
            }
        }
        __syncthreads();
        base[tid] = hist[tid] ? atomicAdd(&binCnt[tid], hist[tid]) : 0;
        cur[tid] = 0;
        __syncthreads();
#pragma unroll
        for (int j = 0; j < J; ++j) {
            if (ok[j]) {
                int slot = base[bn[j]] + atomicAdd(&cur[bn[j]], 1);
                ebuf[bn[j] * CAP + slot] = (unsigned int)s[j] | ((unsigned int)dl[j] << 16);
            }
        }
        return;
    }
    if (bid < BKB + W0B) {
        int idx = (bid - BKB) * 256 + tid;
        int k = idx >> 7, n = idx & 127;            // K=128, N=128
        WT0[(size_t)n * 128 + k] = (_Float16)cw0[idx];
        return;
    }
    if (bid < BKB + W0B + W1B) {
        int idx = (bid - BKB - W0B) * 256 + tid;
        int k = idx >> 6, n = idx & 63;             // K=128, N=64
        WT1[(size_t)n * 128 + k] = (_Float16)cw1[idx];
        return;
    }
    {
        int idx = (bid - BKB - W0B - W1B) * 256 + tid;
        int k = idx >> 5, n = idx & 31;             // K=64, N=32
        WT2[(size_t)n * 64 + k] = (_Float16)cw2[idx];
    }
}

// ---------------- CSR build: per-bin segment + off + dis (self-scans binCnt) ----------------
__global__ __launch_bounds__(256) void k_csrbuild(const unsigned int* __restrict__ ebuf,
        const int* __restrict__ binCnt, int* __restrict__ off, float* __restrict__ dis,
        unsigned short* __restrict__ csr) {
    __shared__ int borig[NBKT];
    __shared__ int bscan[NBKT];
    __shared__ int hist[256];
    __shared__ int sh[256];
    __shared__ int cur[256];
    const int tid = threadIdx.x;
    const int bin = blockIdx.x;

    int bv = binCnt[tid];
    borig[tid] = bv;
    bscan[tid] = bv;
    __syncthreads();
    for (int d = 1; d < NBKT; d <<= 1) {
        int t = (tid >= d) ? bscan[tid - d] : 0;
        __syncthreads();
        bscan[tid] += t;
        __syncthreads();
    }
    const int cnt   = borig[bin];
    const int start = bscan[bin] - cnt;
    const unsigned int* eb = ebuf + (size_t)bin * CAP;

    hist[tid] = 0;
    __syncthreads();
    for (int i = tid; i < cnt; i += 256)
        atomicAdd(&hist[eb[i] >> 16], 1);
    __syncthreads();

    int v = hist[tid];
    sh[tid] = v;
    __syncthreads();
    for (int d = 1; d < 256; d <<= 1) {
        int t = (tid >= d) ? sh[tid - d] : 0;
        __syncthreads();
        sh[tid] += t;
        __syncthreads();
    }
    int gpos = start + sh[tid] - v;

    int node = bin * 256 + tid;
    if (node <= NN) off[node] = gpos;
    if (node < NN)  dis[node] = rsqrtf((float)v + 1.0f);
    cur[tid] = gpos;
    __syncthreads();

    for (int i = tid; i < cnt; i += 256) {
        unsigned int e = eb[i];
        int p = atomicAdd(&cur[e >> 16], 1);
        csr[p] = (unsigned short)(e & 0xFFFFu);
    }
}

// ---------------- MFMA GEMM: g = dis * (X @ WT^T); A is fp32 or fp16 ----------------
template<int K, int DOUT, int SPLIT, bool F32A>
__global__ __launch_bounds__(256) void k_gemm_mfma(const void* __restrict__ Xv,
        const _Float16* __restrict__ WT, const float* __restrict__ dis,
        _Float16* __restrict__ g, int n) {
    constexpr int CW = (DOUT >= 128) ? 2 : 1;
    constexpr int RW = 4 / CW;
    constexpr int NC = DOUT / CW;
    constexpr int NT = NC / 16;
    constexpr int KT = K / 32;
    constexpr int MT = 2;
    constexpr int BR = RW * 32;
    constexpr int SW = DOUT / SPLIT;

    const int tid  = threadIdx.x;
    const int L    = tid & 63;
    const int w    = tid >> 6;
    const int wc   = w % CW;
    const int wr   = w / CW;
    const int r0   = blockIdx.x * BR + wr * 32;
    const int c0   = wc * NC;
    const int quad = L >> 4;
    const int lm   = L & 15;

    float4_t acc[MT][NT];
#pragma unroll
    for (int mt = 0; mt < MT; ++mt)
#pragma unroll
        for (int nt = 0; nt < NT; ++nt) acc[mt][nt] = (float4_t){0.f, 0.f, 0.f, 0.f};

#pragma unroll
    for (int kt = 0; kt < KT; ++kt) {
        half8_t a[MT], b[NT];
#pragma unroll
        for (int mt = 0; mt < MT; ++mt) {
            const size_t roff = (size_t)(r0 + mt * 16 + lm) * K + kt * 32 + quad * 8;
            if (F32A) {
                const float* xr = (const float*)Xv + roff;
                float4 u = *(const float4*)xr;
                float4 v = *(const float4*)(xr + 4);
                a[mt] = (half8_t){(_Float16)u.x, (_Float16)u.y, (_Float16)u.z, (_Float16)u.w,
                                  (_Float16)v.x, (_Float16)v.y, (_Float16)v.z, (_Float16)v.w};
            } else {
                a[mt] = *(const half8_t*)((const _Float16*)Xv + roff);
            }
        }
#pragma unroll
        for (int nt = 0; nt < NT; ++nt)
            b[nt] = *(const half8_t*)(WT + (size_t)(c0 + nt * 16 + lm) * K + kt * 32 + quad * 8);
#pragma unroll
        for (int mt = 0; mt < MT; ++mt)
#pragma unroll
            for (int nt = 0; nt < NT; ++nt)
                acc[mt][nt] = __builtin_amdgcn_mfma_f32_16x16x32_f16(a[mt], b[nt], acc[mt][nt], 0, 0, 0);
    }

#pragma unroll
    for (int mt = 0; mt < MT; ++mt) {
        int rb = r0 + mt * 16 + quad * 4;
        float dv[4];
        *(float4*)dv = *(const float4*)(dis + rb);
#pragma unroll
        for (int nt = 0; nt < NT; ++nt) {
            int c     = c0 + nt * 16 + lm;
            int slice = c / SW;
            int cl    = c - slice * SW;
            _Float16* gp = g + (size_t)slice * n * SW + cl;
#pragma unroll
            for (int reg = 0; reg < 4; ++reg) {
                int r = rb + reg;
                if (r < n) gp[(size_t)r * SW] = (_Float16)(acc[mt][nt][reg] * dv[reg]);
            }
        }
    }
}

// ---------------- one 32-ch slice CSR aggregation (half8 lanes) ----------------
// g: slice base (n x 4 half8); out: Hact half8-base pre-offset to slice column;
// b: 32 bias floats for this slice. out = relu(dis[d]*(g[d]+sum g[s]) + b) fp16.
__global__ __launch_bounds__(256) void k_agg32s(const half8_t* __restrict__ g,
        const float* __restrict__ dis, const float* __restrict__ b,
        const int* __restrict__ off, const unsigned short* __restrict__ csr,
        half8_t* __restrict__ out, int stride8, int n) {
    const int lane = threadIdx.x & 3;         // 4 half8 lanes per node
    const int node = blockIdx.x * 64 + (threadIdx.x >> 2);
    if (node >= n) return;
    float dd = dis[node];
    half8_t hv = g[(size_t)node * 4 + lane];
    float a[8];
#pragma unroll
    for (int j = 0; j < 8; ++j) a[j] = (float)hv[j];
    int e0 = off[node], e1 = off[node + 1];
    int e = e0;
    for (; e + 3 < e1; e += 4) {
        int s0 = csr[e], s1 = csr[e + 1], s2 = csr[e + 2], s3 = csr[e + 3];
        half8_t v0 = g[(size_t)s0 * 4 + lane];
        half8_t v1 = g[(size_t)s1 * 4 + lane];
        half8_t v2 = g[(size_t)s2 * 4 + lane];
        half8_t v3 = g[(size_t)s3 * 4 + lane];
#pragma unroll
        for (int j = 0; j < 8; ++j)
            a[j] += (float)v0[j] + (float)v1[j] + (float)v2[j] + (float)v3[j];
    }
    for (; e < e1; ++e) {
        half8_t v0 = g[(size_t)csr[e] * 4 + lane];
#pragma unroll
        for (int j = 0; j < 8; ++j) a[j] += (float)v0[j];
    }
    half8_t o;
#pragma unroll
    for (int j = 0; j < 8; ++j)
        o[j] = (_Float16)fmaxf(fmaf(a[j], dd, b[lane * 8 + j]), 0.f);
    out[(size_t)node * stride8 + lane] = o;
}

// ---------------- conv2 aggregate (32ch, half8) fused with MLP head ----------------
__global__ __launch_bounds__(256) void k_agg_mlp(const half8_t* __restrict__ g,
        const float* __restrict__ dis, const float* __restrict__ b,
        const int* __restrict__ off, const unsigned short* __restrict__ csr,
        const float* __restrict__ lw0, const float* __restrict__ lb0,
        const float* __restrict__ lw1, const float* __restrict__ lb1,
        const float* __restrict__ lw2, const float* __restrict__ lb2,
        float* __restrict__ sv, int n) {
    __shared__ float sh[64 * 33];
    const int tid  = threadIdx.x;
    const int lane = tid & 3;
    const int ln   = tid >> 2;                 // 64 nodes per block
    const int node = blockIdx.x * 64 + ln;

    if (node < n) {
        float dd = dis[node];
        half8_t hv = g[(size_t)node * 4 + lane];
        float a[8];
#pragma unroll
        for (int j = 0; j < 8; ++j) a[j] = (float)hv[j];
        int e0 = off[node], e1 = off[node + 1];
        int e = e0;
        for (; e + 3 < e1; e += 4) {
            int s0 = csr[e], s1 = csr[e + 1], s2 = csr[e + 2], s3 = csr[e + 3];
            half8_t v0 = g[(size_t)s0 * 4 + lane];
            half8_t v1 = g[(size_t)s1 * 4 + lane];
            half8_t v2 = g[(size_t)s2 * 4 + lane];
            half8_t v3 = g[(size_t)s3 * 4 + lane];
#pragma unroll
            for (int j = 0; j < 8; ++j)
                a[j] += (float)v0[j] + (float)v1[j] + (float)v2[j] + (float)v3[j];
        }
        for (; e < e1; ++e) {
            half8_t v0 = g[(size_t)csr[e] * 4 + lane];
#pragma unroll
            for (int j = 0; j < 8; ++j) a[j] += (float)v0[j];
        }
        float* row = sh + ln * 33 + lane * 8;
#pragma unroll
        for (int j = 0; j < 8; ++j)
            row[j] = fmaxf(fmaf(a[j], dd, b[lane * 8 + j]), 0.f);
    }
    __syncthreads();

    if (tid < 64) {
        int node2 = blockIdx.x * 64 + tid;
        if (node2 < n) {
            const float* v = sh + tid * 33;
            float a[16];
#pragma unroll
            for (int j = 0; j < 16; ++j) {
                float acc = lb0[j];
#pragma unroll
                for (int k = 0; k < 32; ++k) acc = fmaf(v[k], lw0[k * 16 + j], acc);
                a[j] = fmaxf(acc, 0.f);
            }
            float b8[8];
#pragma unroll
            for (int j = 0; j < 8; ++j) {
                float acc = lb1[j];
#pragma unroll
                for (int k = 0; k < 16; ++k) acc = fmaf(a[k], lw1[k * 8 + j], acc);
                b8[j] = fmaxf(acc, 0.f);
            }
            float z = lb2[0];
#pragma unroll
            for (int k = 0; k < 8; ++k) z = fmaf(b8[k], lw2[k], z);
            sv[node2] = 1.0f / (1.0f + expf(-z));
        }
    }
}

// ---------------- link prediction: 2 edges per thread ----------------
__global__ void k_pred(const float* __restrict__ s, const int* __restrict__ pe,
                       float* __restrict__ out, int ep2) {
    int i = blockIdx.x * blockDim.x + threadIdx.x;
    if (i >= ep2) return;
    int4 p = ((const int4*)pe)[i];
    float2 o;
    o.x = s[p.x] * s[p.y];
    o.y = s[p.z] * s[p.w];
    ((float2*)out)[i] = o;
}

extern "C" void kernel_launch(void* const* d_in, const int* in_sizes, int n_in,
                              void* d_out, int out_size, void* d_ws, size_t ws_size,
                              hipStream_t stream) {
    const float* x   = (const float*)d_in[0];
    const int*   ei  = (const int*)d_in[1];
    const int*   pe  = (const int*)d_in[2];
    const float* cw0 = (const float*)d_in[3];
    const float* cb0 = (const float*)d_in[4];
    const float* cw1 = (const float*)d_in[5];
    const float* cb1 = (const float*)d_in[6];
    const float* cw2 = (const float*)d_in[7];
    const float* cb2 = (const float*)d_in[8];
    const float* lw0 = (const float*)d_in[9];
    const float* lb0 = (const float*)d_in[10];
    const float* lw1 = (const float*)d_in[11];
    const float* lb1 = (const float*)d_in[12];
    const float* lw2 = (const float*)d_in[13];
    const float* lb2 = (const float*)d_in[14];

    const int* src = ei;        // edge_index[0]
    const int* dst = ei + NE;   // edge_index[1]

    // workspace layout
    char* w = (char*)d_ws;
    float*          dis  = (float*)w;           w += sizeof(float) * NN;
    _Float16*       A    = (_Float16*)w;        w += sizeof(_Float16) * (size_t)NN * 128;
    _Float16*       Hact = (_Float16*)w;        w += sizeof(_Float16) * (size_t)NP * 128;
    float*          sv   = (float*)w;           w += sizeof(float) * NN;
    _Float16*       WT0  = (_Float16*)w;        w += sizeof(_Float16) * 128 * 128;
    _Float16*       WT1  = (_Float16*)w;        w += sizeof(_Float16) * 64 * 128;
    _Float16*       WT2  = (_Float16*)w;        w += sizeof(_Float16) * 32 * 64;
    int*            off  = (int*)w;             w += sizeof(int) * (NN + 1);
    unsigned short* csr  = (unsigned short*)w;  w += sizeof(unsigned short) * NE;
    int*            binCnt = (int*)w;           w += sizeof(int) * NBKT;
    unsigned int*   ebuf = (unsigned int*)w;    w += sizeof(unsigned int) * (size_t)NBKT * CAP;

    const int T = 256;
    half8_t* A8    = (half8_t*)A;
    half8_t* Hact8 = (half8_t*)Hact;

    // --- front end: bucket + weight transposes ---
    hipMemsetAsync(binCnt, 0, sizeof(int) * NBKT, stream);
    k_front<<<FRONT_BLOCKS, 256, 0, stream>>>(src, dst, binCnt, ebuf,
                                              cw0, WT0, cw1, WT1, cw2, WT2);

    // --- CSR build ---
    k_csrbuild<<<NBKT, 256, 0, stream>>>(ebuf, binCnt, off, dis, csr);

    // --- conv0: 128 -> 128, fp32 A; 4 sequential 32-ch slice aggregations ---
    k_gemm_mfma<128, 128, 4, true><<<NP / 64, 256, 0, stream>>>(x, WT0, dis, A, NN);
    for (int s = 0; s < 4; ++s)
        k_agg32s<<<NODE_BLKS64, 256, 0, stream>>>(A8 + (size_t)s * NN * 4, dis, cb0 + s * 32,
                                                  off, csr, Hact8 + s * 4, 16, NN);

    // --- conv1: 128 -> 64; 2 sequential slice aggregations ---
    k_gemm_mfma<128, 64, 2, false><<<NP / 128, 256, 0, stream>>>(Hact, WT1, dis, A, NN);
    for (int s = 0; s < 2; ++s)
        k_agg32s<<<NODE_BLKS64, 256, 0, stream>>>(A8 + (size_t)s * NN * 4, dis, cb1 + s * 32,
                                                  off, csr, Hact8 + s * 4, 8, NN);

    // --- conv2: 64 -> 32; aggregate fused with MLP ---
    k_gemm_mfma<64, 32, 1, false><<<NP / 128, 256, 0, stream>>>(Hact, WT2, dis, A, NN);
    k_agg_mlp<<<NODE_BLKS64, 256, 0, stream>>>(A8, dis, cb2, off, csr,
                                               lw0, lb0, lw1, lb1, lw2, lb2, sv, NN);

    // --- link prediction ---
    k_pred<<<cdiv(NEP / 2, T), T, 0, stream>>>(sv, pe, (float*)d_out, NEP / 2);
}

// Round 11
// 236.406 us; speedup vs baseline: 1.0770x; 1.0511x over previous
//
#include <hip/hip_runtime.h>
#include <math.h>

constexpr int NN  = 50000;   // nodes (< 65536 -> csr fits in ushort)
constexpr int NP  = 50048;   // padded rows (multiple of 128)
constexpr int NE  = 800000;  // edges
constexpr int NEP = 200000;  // pred edges

// CSR-build binning
constexpr int NBKT  = 256;   // bins; bin = dst >> 8
constexpr int CAP   = 4096;  // per-bin ebuf capacity (mean 3125, ~17 sigma slack)
constexpr int CAPC  = 4096;  // per-bin csr region (padded total mean ~3500, safe)
constexpr int CHUNK = 4096;  // edges per bucket workgroup

// fused front-end block ranges
constexpr int BKB = (NE + CHUNK - 1) / CHUNK;          // 196 bucket blocks
constexpr int W0B = 128 * 128 / 256;                   // 64
constexpr int W1B = 128 * 64 / 256;                    // 32
constexpr int W2B = 64 * 32 / 256;                     // 8
constexpr int FRONT_BLOCKS = BKB + W0B + W1B + W2B;

constexpr int NODE_BLKS32 = (NN + 31) / 32;            // 1563 blocks @ 32 nodes (8 lanes/node)

typedef _Float16 half4_t __attribute__((ext_vector_type(4)));
typedef _Float16 half8_t __attribute__((ext_vector_type(8)));
typedef float    float4_t __attribute__((ext_vector_type(4)));

static inline int cdiv(long long a, int b) { return (int)((a + b - 1) / b); }

// ---------------- fused front end: bucket edges + W transposes ----------------
__global__ __launch_bounds__(256) void k_front(const int* __restrict__ src,
        const int* __restrict__ dst, int* __restrict__ binCnt,
        unsigned int* __restrict__ ebuf,
        const float* __restrict__ cw0, _Float16* __restrict__ WT0,
        const float* __restrict__ cw1, _Float16* __restrict__ WT1,
        const float* __restrict__ cw2, _Float16* __restrict__ WT2) {
    const int tid = threadIdx.x;
    const int bid = blockIdx.x;

    if (bid < BKB) {
        __shared__ int hist[NBKT];
        __shared__ int base[NBKT];
        __shared__ int cur[NBKT];
        constexpr int J = CHUNK / 256;   // 16 edges per thread
        const int e0 = bid * CHUNK;
        hist[tid] = 0;
        __syncthreads();
        int  s[J], bn[J], dl[J];
        bool ok[J];
#pragma unroll
        for (int j = 0; j < J; ++j) {
            int i = e0 + j * 256 + tid;
            ok[j] = i < NE;
            if (ok[j]) {
                int d = dst[i];
                s[j]  = src[i];
                bn[j] = d >> 8;
                dl[j] = d & 255;
                atomicAdd(&hist[bn[j]], 1);
            }
        }
        __syncthreads();
        base[tid] = hist[tid] ? atomicAdd(&binCnt[tid], hist[tid]) : 0;
        cur[tid] = 0;
        __syncthreads();
#pragma unroll
        for (int j = 0; j < J; ++j) {
            if (ok[j]) {
                int slot = base[bn[j]] + atomicAdd(&cur[bn[j]], 1);
                ebuf[bn[j] * CAP + slot] = (unsigned int)s[j] | ((unsigned int)dl[j] << 16);
            }
        }
        return;
    }
    if (bid < BKB + W0B) {
        int idx = (bid - BKB) * 256 + tid;
        int k = idx >> 7, n = idx & 127;            // K=128, N=128
        WT0[(size_t)n * 128 + k] = (_Float16)cw0[idx];
        return;
    }
    if (bid < BKB + W0B + W1B) {
        int idx = (bid - BKB - W0B) * 256 + tid;
        int k = idx >> 6, n = idx & 63;             // K=128, N=64
        WT1[(size_t)n * 128 + k] = (_Float16)cw1[idx];
        return;
    }
    {
        int idx = (bid - BKB - W0B - W1B) * 256 + tid;
        int k = idx >> 5, n = idx & 31;             // K=64, N=32
        WT2[(size_t)n * 64 + k] = (_Float16)cw2[idx];
    }
}

// ---------------- CSR build: per-bin fixed region, segments padded to x4 ----------------
// off[node] = start | (paddedCnt << 20); pads point at zero-row index NN.
__global__ __launch_bounds__(256) void k_csrbuild(const unsigned int* __restrict__ ebuf,
        const int* __restrict__ binCnt, int* __restrict__ off, float* __restrict__ dis,
        unsigned short* __restrict__ csr) {
    __shared__ int hist[256];
    __shared__ int sh[256];
    __shared__ int cur[256];
    const int tid = threadIdx.x;
    const int bin = blockIdx.x;
    const int cnt = binCnt[bin];
    const unsigned int* eb = ebuf + (size_t)bin * CAP;

    hist[tid] = 0;
    __syncthreads();
    for (int i = tid; i < cnt; i += 256)
        atomicAdd(&hist[eb[i] >> 16], 1);
    __syncthreads();

    int v  = hist[tid];
    int pv = (v + 3) & ~3;                 // padded to multiple of 4
    sh[tid] = pv;
    __syncthreads();
    for (int d = 1; d < 256; d <<= 1) {
        int t = (tid >= d) ? sh[tid - d] : 0;
        __syncthreads();
        sh[tid] += t;
        __syncthreads();
    }
    int start = bin * CAPC + (sh[tid] - pv);   // local exclusive prefix of pv

    int node = bin * 256 + tid;
    if (node < NN) {
        off[node] = start | (pv << 20);
        dis[node] = rsqrtf((float)v + 1.0f);
    }
    cur[tid] = start;
    __syncthreads();

    for (int i = tid; i < cnt; i += 256) {
        unsigned int e = eb[i];
        int p = atomicAdd(&cur[e >> 16], 1);
        csr[p] = (unsigned short)(e & 0xFFFFu);
    }
    // pads (disjoint from scattered region; no barrier needed)
    for (int k2 = v; k2 < pv; ++k2) csr[start + k2] = (unsigned short)NN;
}

// ---------------- MFMA GEMM: g = dis * (X @ WT^T); A fp32 or fp16 ----------------
// Messages in SPLIT slices, each (n+1) x SW fp16; row n of each slice = zeros.
template<int K, int DOUT, int SPLIT, bool F32A>
__global__ __launch_bounds__(256) void k_gemm_mfma(const void* __restrict__ Xv,
        const _Float16* __restrict__ WT, const float* __restrict__ dis,
        _Float16* __restrict__ g, int n) {
    constexpr int CW = (DOUT >= 128) ? 2 : 1;
    constexpr int RW = 4 / CW;
    constexpr int NC = DOUT / CW;
    constexpr int NT = NC / 16;
    constexpr int KT = K / 32;
    constexpr int MT = 2;
    constexpr int BR = RW * 32;
    constexpr int SW = DOUT / SPLIT;

    const int tid  = threadIdx.x;
    const int L    = tid & 63;
    const int w    = tid >> 6;
    const int wc   = w % CW;
    const int wr   = w / CW;
    const int r0   = blockIdx.x * BR + wr * 32;
    const int c0   = wc * NC;
    const int quad = L >> 4;
    const int lm   = L & 15;

    float4_t acc[MT][NT];
#pragma unroll
    for (int mt = 0; mt < MT; ++mt)
#pragma unroll
        for (int nt = 0; nt < NT; ++nt) acc[mt][nt] = (float4_t){0.f, 0.f, 0.f, 0.f};

#pragma unroll
    for (int kt = 0; kt < KT; ++kt) {
        half8_t a[MT], b[NT];
#pragma unroll
        for (int mt = 0; mt < MT; ++mt) {
            const size_t roff = (size_t)(r0 + mt * 16 + lm) * K + kt * 32 + quad * 8;
            if (F32A) {
                const float* xr = (const float*)Xv + roff;
                float4 u = *(const float4*)xr;
                float4 v = *(const float4*)(xr + 4);
                a[mt] = (half8_t){(_Float16)u.x, (_Float16)u.y, (_Float16)u.z, (_Float16)u.w,
                                  (_Float16)v.x, (_Float16)v.y, (_Float16)v.z, (_Float16)v.w};
            } else {
                a[mt] = *(const half8_t*)((const _Float16*)Xv + roff);
            }
        }
#pragma unroll
        for (int nt = 0; nt < NT; ++nt)
            b[nt] = *(const half8_t*)(WT + (size_t)(c0 + nt * 16 + lm) * K + kt * 32 + quad * 8);
#pragma unroll
        for (int mt = 0; mt < MT; ++mt)
#pragma unroll
            for (int nt = 0; nt < NT; ++nt)
                acc[mt][nt] = __builtin_amdgcn_mfma_f32_16x16x32_f16(a[mt], b[nt], acc[mt][nt], 0, 0, 0);
    }

#pragma unroll
    for (int mt = 0; mt < MT; ++mt) {
        int rb = r0 + mt * 16 + quad * 4;
        float dv[4];
        *(float4*)dv = *(const float4*)(dis + rb);
#pragma unroll
        for (int nt = 0; nt < NT; ++nt) {
            int c     = c0 + nt * 16 + lm;
            int slice = c / SW;
            int cl    = c - slice * SW;
            _Float16* gp = g + (size_t)slice * (n + 1) * SW + cl;
#pragma unroll
            for (int reg = 0; reg < 4; ++reg) {
                int r = rb + reg;
                if (r < n)       gp[(size_t)r * SW] = (_Float16)(acc[mt][nt][reg] * dv[reg]);
                else if (r == n) gp[(size_t)r * SW] = (_Float16)0.f;   // zero row for pads
            }
        }
    }
}

// ---------------- one 32-ch slice aggregation: 8 lanes/node, 2 edge groups ----------------
// lanes 0-3 even csr quads, 4-7 odd quads; merged via shfl_xor(4).
__global__ __launch_bounds__(256) void k_agg32s(const half8_t* __restrict__ g,
        const float* __restrict__ dis, const float* __restrict__ b,
        const int* __restrict__ off, const unsigned short* __restrict__ csr,
        half8_t* __restrict__ out, int stride8, int n) {
    const int l8   = threadIdx.x & 7;
    const int lane = l8 & 3;
    const int grp  = l8 >> 2;
    const int node = blockIdx.x * 32 + (threadIdx.x >> 3);
    if (node >= n) return;

    float dd = dis[node];
    half8_t hv = g[(size_t)node * 4 + lane];
    float a[8];
#pragma unroll
    for (int j = 0; j < 8; ++j) a[j] = (grp == 0) ? (float)hv[j] : 0.f;

    int pk = off[node];
    int e0 = pk & 0xFFFFF;
    int e1 = e0 + (pk >> 20);
    for (int e = e0 + grp * 4; e < e1; e += 8) {
        ushort4 c4 = *(const ushort4*)(csr + e);
        half8_t v0 = g[(size_t)c4.x * 4 + lane];
        half8_t v1 = g[(size_t)c4.y * 4 + lane];
        half8_t v2 = g[(size_t)c4.z * 4 + lane];
        half8_t v3 = g[(size_t)c4.w * 4 + lane];
#pragma unroll
        for (int j = 0; j < 8; ++j)
            a[j] += (float)v0[j] + (float)v1[j] + (float)v2[j] + (float)v3[j];
    }
#pragma unroll
    for (int j = 0; j < 8; ++j) a[j] += __shfl_xor(a[j], 4);

    if (grp == 0) {
        half8_t o;
#pragma unroll
        for (int j = 0; j < 8; ++j)
            o[j] = (_Float16)fmaxf(fmaf(a[j], dd, b[lane * 8 + j]), 0.f);
        out[(size_t)node * stride8 + lane] = o;
    }
}

// ---------------- conv2 aggregate (32ch) fused with MLP head ----------------
__global__ __launch_bounds__(256) void k_agg_mlp(const half8_t* __restrict__ g,
        const float* __restrict__ dis, const float* __restrict__ b,
        const int* __restrict__ off, const unsigned short* __restrict__ csr,
        const float* __restrict__ lw0, const float* __restrict__ lb0,
        const float* __restrict__ lw1, const float* __restrict__ lb1,
        const float* __restrict__ lw2, const float* __restrict__ lb2,
        float* __restrict__ sv, int n) {
    __shared__ float sh[32 * 33];
    const int tid  = threadIdx.x;
    const int l8   = tid & 7;
    const int lane = l8 & 3;
    const int grp  = l8 >> 2;
    const int ln   = tid >> 3;               // 32 nodes per block
    const int node = blockIdx.x * 32 + ln;

    if (node < n) {
        float dd = dis[node];
        half8_t hv = g[(size_t)node * 4 + lane];
        float a[8];
#pragma unroll
        for (int j = 0; j < 8; ++j) a[j] = (grp == 0) ? (float)hv[j] : 0.f;
        int pk = off[node];
        int e0 = pk & 0xFFFFF;
        int e1 = e0 + (pk >> 20);
        for (int e = e0 + grp * 4; e < e1; e += 8) {
            ushort4 c4 = *(const ushort4*)(csr + e);
            half8_t v0 = g[(size_t)c4.x * 4 + lane];
            half8_t v1 = g[(size_t)c4.y * 4 + lane];
            half8_t v2 = g[(size_t)c4.z * 4 + lane];
            half8_t v3 = g[(size_t)c4.w * 4 + lane];
#pragma unroll
            for (int j = 0; j < 8; ++j)
                a[j] += (float)v0[j] + (float)v1[j] + (float)v2[j] + (float)v3[j];
        }
#pragma unroll
        for (int j = 0; j < 8; ++j) a[j] += __shfl_xor(a[j], 4);
        if (grp == 0) {
            float* row = sh + ln * 33 + lane * 8;
#pragma unroll
            for (int j = 0; j < 8; ++j)
                row[j] = fmaxf(fmaf(a[j], dd, b[lane * 8 + j]), 0.f);
        }
    }
    __syncthreads();

    if (tid < 32) {
        int node2 = blockIdx.x * 32 + tid;
        if (node2 < n) {
            const float* v = sh + tid * 33;
            float a[16];
#pragma unroll
            for (int j = 0; j < 16; ++j) {
                float acc = lb0[j];
#pragma unroll
                for (int k = 0; k < 32; ++k) acc = fmaf(v[k], lw0[k * 16 + j], acc);
                a[j] = fmaxf(acc, 0.f);
            }
            float b8[8];
#pragma unroll
            for (int j = 0; j < 8; ++j) {
                float acc = lb1[j];
#pragma unroll
                for (int k = 0; k < 16; ++k) acc = fmaf(a[k], lw1[k * 8 + j], acc);
                b8[j] = fmaxf(acc, 0.f);
            }
            float z = lb2[0];
#pragma unroll
            for (int k = 0; k < 8; ++k) z = fmaf(b8[k], lw2[k], z);
            sv[node2] = 1.0f / (1.0f + expf(-z));
        }
    }
}

// ---------------- link prediction: 2 edges per thread ----------------
__global__ void k_pred(const float* __restrict__ s, const int* __restrict__ pe,
                       float* __restrict__ out, int ep2) {
    int i = blockIdx.x * blockDim.x + threadIdx.x;
    if (i >= ep2) return;
    int4 p = ((const int4*)pe)[i];
    float2 o;
    o.x = s[p.x] * s[p.y];
    o.y = s[p.z] * s[p.w];
    ((float2*)out)[i] = o;
}

extern "C" void kernel_launch(void* const* d_in, const int* in_sizes, int n_in,
                              void* d_out, int out_size, void* d_ws, size_t ws_size,
                              hipStream_t stream) {
    const float* x   = (const float*)d_in[0];
    const int*   ei  = (const int*)d_in[1];
    const int*   pe  = (const int*)d_in[2];
    const float* cw0 = (const float*)d_in[3];
    const float* cb0 = (const float*)d_in[4];
    const float* cw1 = (const float*)d_in[5];
    const float* cb1 = (const float*)d_in[6];
    const float* cw2 = (const float*)d_in[7];
    const float* cb2 = (const float*)d_in[8];
    const float* lw0 = (const float*)d_in[9];
    const float* lb0 = (const float*)d_in[10];
    const float* lw1 = (const float*)d_in[11];
    const float* lb1 = (const float*)d_in[12];
    const float* lw2 = (const float*)d_in[13];
    const float* lb2 = (const float*)d_in[14];

    const int* src = ei;        // edge_index[0]
    const int* dst = ei + NE;   // edge_index[1]

    // workspace layout
    char* w = (char*)d_ws;
    float*          dis  = (float*)w;           w += sizeof(float) * NN;
    _Float16*       A    = (_Float16*)w;        w += sizeof(_Float16) * (size_t)(NN + 1) * 128;
    _Float16*       Hact = (_Float16*)w;        w += sizeof(_Float16) * (size_t)NP * 128;
    float*          sv   = (float*)w;           w += sizeof(float) * NN;
    _Float16*       WT0  = (_Float16*)w;        w += sizeof(_Float16) * 128 * 128;
    _Float16*       WT1  = (_Float16*)w;        w += sizeof(_Float16) * 64 * 128;
    _Float16*       WT2  = (_Float16*)w;        w += sizeof(_Float16) * 32 * 64;
    int*            off  = (int*)w;             w += sizeof(int) * NN;
    unsigned short* csr  = (unsigned short*)w;  w += sizeof(unsigned short) * (size_t)NBKT * CAPC;
    int*            binCnt = (int*)w;           w += sizeof(int) * NBKT;
    unsigned int*   ebuf = (unsigned int*)w;    w += sizeof(unsigned int) * (size_t)NBKT * CAP;

    const int T = 256;
    half8_t* A8    = (half8_t*)A;
    half8_t* Hact8 = (half8_t*)Hact;
    const size_t SLICE8 = (size_t)(NN + 1) * 4;   // half8 per 32-ch slice

    // --- front end: bucket + weight transposes ---
    hipMemsetAsync(binCnt, 0, sizeof(int) * NBKT, stream);
    k_front<<<FRONT_BLOCKS, 256, 0, stream>>>(src, dst, binCnt, ebuf,
                                              cw0, WT0, cw1, WT1, cw2, WT2);

    // --- CSR build (padded segments, per-bin regions) ---
    k_csrbuild<<<NBKT, 256, 0, stream>>>(ebuf, binCnt, off, dis, csr);

    // --- conv0: 128 -> 128, fp32 A; 4 sequential 32-ch slice aggregations ---
    k_gemm_mfma<128, 128, 4, true><<<NP / 64, 256, 0, stream>>>(x, WT0, dis, A, NN);
    for (int s = 0; s < 4; ++s)
        k_agg32s<<<NODE_BLKS32, 256, 0, stream>>>(A8 + s * SLICE8, dis, cb0 + s * 32,
                                                  off, csr, Hact8 + s * 4, 16, NN);

    // --- conv1: 128 -> 64; 2 sequential slice aggregations ---
    k_gemm_mfma<128, 64, 2, false><<<NP / 128, 256, 0, stream>>>(Hact, WT1, dis, A, NN);
    for (int s = 0; s < 2; ++s)
        k_agg32s<<<NODE_BLKS32, 256, 0, stream>>>(A8 + s * SLICE8, dis, cb1 + s * 32,
                                                  off, csr, Hact8 + s * 4, 8, NN);

    // --- conv2: 64 -> 32; aggregate fused with MLP ---
    k_gemm_mfma<64, 32, 1, false><<<NP / 128, 256, 0, stream>>>(Hact, WT2, dis, A, NN);
    k_agg_mlp<<<NODE_BLKS32, 256, 0, stream>>>(A8, dis, cb2, off, csr,
                                               lw0, lb0, lw1, lb1, lw2, lb2, sv, NN);

    // --- link prediction ---
    k_pred<<<cdiv(NEP / 2, T), T, 0, stream>>>(sv, pe, (float*)d_out, NEP / 2);
}

// Round 12
// 217.827 us; speedup vs baseline: 1.1689x; 1.0853x over previous
//
#include <hip/hip_runtime.h>
#include <math.h>

constexpr int NN  = 50000;   // nodes (< 65536 -> csr fits in ushort)
constexpr int NP  = 50048;   // padded rows (multiple of 128)
constexpr int NE  = 800000;  // edges
constexpr int NEP = 200000;  // pred edges

// CSR-build binning
constexpr int NBKT  = 256;   // bins; bin = dst >> 8
constexpr int CAP   = 4096;  // per-bin ebuf capacity
constexpr int CAPC  = 4096;  // per-bin csr region
constexpr int CHUNK = 4096;  // edges per bucket workgroup

constexpr int BKB = (NE + CHUNK - 1) / CHUNK;          // 196 bucket blocks
constexpr int W0B = 128 * 128 / 256;                   // 64
constexpr int W1B = 128 * 64 / 256;                    // 32
constexpr int W2B = 64 * 32 / 256;                     // 8
constexpr int FRONT_BLOCKS = BKB + W0B + W1B + W2B;

constexpr int NODE_BLKS32 = (NN + 31) / 32;            // 1563 blocks @ 32 nodes

typedef _Float16 half8_t __attribute__((ext_vector_type(8)));
typedef float    float4_t __attribute__((ext_vector_type(4)));

static inline int cdiv(long long a, int b) { return (int)((a + b - 1) / b); }

// ---------------- fused front end: bucket edges + W transposes ----------------
__global__ __launch_bounds__(256) void k_front(const int* __restrict__ src,
        const int* __restrict__ dst, int* __restrict__ binCnt,
        unsigned int* __restrict__ ebuf,
        const float* __restrict__ cw0, _Float16* __restrict__ WT0,
        const float* __restrict__ cw1, _Float16* __restrict__ WT1,
        const float* __restrict__ cw2, _Float16* __restrict__ WT2) {
    const int tid = threadIdx.x;
    const int bid = blockIdx.x;

    if (bid < BKB) {
        __shared__ int hist[NBKT];
        __shared__ int base[NBKT];
        __shared__ int cur[NBKT];
        constexpr int J = CHUNK / 256;   // 16 edges per thread
        const int e0 = bid * CHUNK;
        hist[tid] = 0;
        __syncthreads();
        int  s[J], bn[J], dl[J];
        bool ok[J];
#pragma unroll
        for (int j = 0; j < J; ++j) {
            int i = e0 + j * 256 + tid;
            ok[j] = i < NE;
            if (ok[j]) {
                int d = dst[i];
                s[j]  = src[i];
                bn[j] = d >> 8;
                dl[j] = d & 255;
                atomicAdd(&hist[bn[j]], 1);
            }
        }
        __syncthreads();
        base[tid] = hist[tid] ? atomicAdd(&binCnt[tid], hist[tid]) : 0;
        cur[tid] = 0;
        __syncthreads();
#pragma unroll
        for (int j = 0; j < J; ++j) {
            if (ok[j]) {
                int slot = base[bn[j]] + atomicAdd(&cur[bn[j]], 1);
                ebuf[bn[j] * CAP + slot] = (unsigned int)s[j] | ((unsigned int)dl[j] << 16);
            }
        }
        return;
    }
    if (bid < BKB + W0B) {
        int idx = (bid - BKB) * 256 + tid;
        int k = idx >> 7, n = idx & 127;            // K=128, N=128
        WT0[(size_t)n * 128 + k] = (_Float16)cw0[idx];
        return;
    }
    if (bid < BKB + W0B + W1B) {
        int idx = (bid - BKB - W0B) * 256 + tid;
        int k = idx >> 6, n = idx & 63;             // K=128, N=64
        WT1[(size_t)n * 128 + k] = (_Float16)cw1[idx];
        return;
    }
    {
        int idx = (bid - BKB - W0B - W1B) * 256 + tid;
        int k = idx >> 5, n = idx & 31;             // K=64, N=32
        WT2[(size_t)n * 64 + k] = (_Float16)cw2[idx];
    }
}

// ---------------- CSR build: per-bin fixed region, segments padded to x4 ----------------
// off[node] = start | (paddedCnt << 20); pads point at zero-row index NN.
__global__ __launch_bounds__(256) void k_csrbuild(const unsigned int* __restrict__ ebuf,
        const int* __restrict__ binCnt, int* __restrict__ off, float* __restrict__ dis,
        unsigned short* __restrict__ csr) {
    __shared__ int hist[256];
    __shared__ int sh[256];
    __shared__ int cur[256];
    const int tid = threadIdx.x;
    const int bin = blockIdx.x;
    const int cnt = binCnt[bin];
    const unsigned int* eb = ebuf + (size_t)bin * CAP;

    hist[tid] = 0;
    __syncthreads();
    for (int i = tid; i < cnt; i += 256)
        atomicAdd(&hist[eb[i] >> 16], 1);
    __syncthreads();

    int v  = hist[tid];
    int pv = (v + 3) & ~3;
    sh[tid] = pv;
    __syncthreads();
    for (int d = 1; d < 256; d <<= 1) {
        int t = (tid >= d) ? sh[tid - d] : 0;
        __syncthreads();
        sh[tid] += t;
        __syncthreads();
    }
    int start = bin * CAPC + (sh[tid] - pv);

    int node = bin * 256 + tid;
    if (node < NN) {
        off[node] = start | (pv << 20);
        dis[node] = rsqrtf((float)v + 1.0f);
    }
    cur[tid] = start;
    __syncthreads();

    for (int i = tid; i < cnt; i += 256) {
        unsigned int e = eb[i];
        int p = atomicAdd(&cur[e >> 16], 1);
        csr[p] = (unsigned short)(e & 0xFFFFu);
    }
    for (int k2 = v; k2 < pv; ++k2) csr[start + k2] = (unsigned short)NN;
}

// ---------------- MFMA GEMM (conv0): msg0 = dis * (x_fp32 @ WT0^T) ----------------
// Output (n+1) x 128 fp16; row n zeroed (pad target).
__global__ __launch_bounds__(256) void k_gemm0(const float* __restrict__ X,
        const _Float16* __restrict__ WT, const float* __restrict__ dis,
        _Float16* __restrict__ g, int n) {
    constexpr int K = 128, DOUT = 128;
    constexpr int NC = 64, NT = 4, KT = 4, MT = 2;

    const int tid  = threadIdx.x;
    const int L    = tid & 63;
    const int w    = tid >> 6;
    const int wc   = w & 1;
    const int wr   = w >> 1;
    const int r0   = blockIdx.x * 64 + wr * 32;
    const int c0   = wc * NC;
    const int quad = L >> 4;
    const int lm   = L & 15;

    float4_t acc[MT][NT];
#pragma unroll
    for (int mt = 0; mt < MT; ++mt)
#pragma unroll
        for (int nt = 0; nt < NT; ++nt) acc[mt][nt] = (float4_t){0.f, 0.f, 0.f, 0.f};

#pragma unroll
    for (int kt = 0; kt < KT; ++kt) {
        half8_t a[MT], b[NT];
#pragma unroll
        for (int mt = 0; mt < MT; ++mt) {
            const float* xr = X + (size_t)(r0 + mt * 16 + lm) * K + kt * 32 + quad * 8;
            float4 u = *(const float4*)xr;
            float4 v = *(const float4*)(xr + 4);
            a[mt] = (half8_t){(_Float16)u.x, (_Float16)u.y, (_Float16)u.z, (_Float16)u.w,
                              (_Float16)v.x, (_Float16)v.y, (_Float16)v.z, (_Float16)v.w};
        }
#pragma unroll
        for (int nt = 0; nt < NT; ++nt)
            b[nt] = *(const half8_t*)(WT + (size_t)(c0 + nt * 16 + lm) * K + kt * 32 + quad * 8);
#pragma unroll
        for (int mt = 0; mt < MT; ++mt)
#pragma unroll
            for (int nt = 0; nt < NT; ++nt)
                acc[mt][nt] = __builtin_amdgcn_mfma_f32_16x16x32_f16(a[mt], b[nt], acc[mt][nt], 0, 0, 0);
    }

#pragma unroll
    for (int mt = 0; mt < MT; ++mt) {
        int rb = r0 + mt * 16 + quad * 4;
        float dv[4];
        *(float4*)dv = *(const float4*)(dis + rb);
#pragma unroll
        for (int nt = 0; nt < NT; ++nt) {
            int c = c0 + nt * 16 + lm;
#pragma unroll
            for (int reg = 0; reg < 4; ++reg) {
                int r = rb + reg;
                if (r < n)       g[(size_t)r * DOUT + c] = (_Float16)(acc[mt][nt][reg] * dv[reg]);
                else if (r == n) g[(size_t)r * DOUT + c] = (_Float16)0.f;
            }
        }
    }
}

// ---------------- fused aggregate + GEMM ----------------
// Phase A: 32 nodes/block, 8 lanes/node aggregate DIN ch of gin (prescaled msgs),
//          apply dis*acc+bias, relu, deposit fp16 tile in LDS (padded stride).
// Phase B: 32 x DOUT MFMA from LDS vs WT; write prescaled fp16 messages gout.
// gout has n+1 rows; row n zeroed (pad target for next layer's csr pads).
template<int DIN, int DOUT>
__global__ __launch_bounds__(256) void k_agg_gemm(const half8_t* __restrict__ gin,
        const float* __restrict__ dis, const float* __restrict__ bias,
        const int* __restrict__ off, const unsigned short* __restrict__ csr,
        const _Float16* __restrict__ WT, _Float16* __restrict__ gout, int n) {
    constexpr int R8  = DIN / 8;        // half8 per input row
    constexpr int HPL = R8 / 8;         // half8 per lane (8 lanes/node)
    constexpr int XS  = DIN + 8;        // padded LDS row stride (fp16): +16B -> 2-way-only aliasing
    __shared__ _Float16 sX[32 * XS];

    const int tid  = threadIdx.x;
    const int l8   = tid & 7;
    const int ln   = tid >> 3;          // local node 0..31
    const int r0   = blockIdx.x * 32;
    const int node = r0 + ln;

    // ---- phase A ----
    if (node < n) {
        float dd = dis[node];
        float a[HPL * 8];
#pragma unroll
        for (int h = 0; h < HPL; ++h) {
            half8_t hv = gin[(size_t)node * R8 + l8 * HPL + h];
#pragma unroll
            for (int j = 0; j < 8; ++j) a[h * 8 + j] = (float)hv[j];
        }
        int pk = off[node];
        int e0 = pk & 0xFFFFF;
        int e1 = e0 + (pk >> 20);
        for (int e = e0; e < e1; e += 4) {
            ushort4 c4 = *(const ushort4*)(csr + e);
            int sidx[4] = {c4.x, c4.y, c4.z, c4.w};
#pragma unroll
            for (int q = 0; q < 4; ++q) {
#pragma unroll
                for (int h = 0; h < HPL; ++h) {
                    half8_t v = gin[(size_t)sidx[q] * R8 + l8 * HPL + h];
#pragma unroll
                    for (int j = 0; j < 8; ++j) a[h * 8 + j] += (float)v[j];
                }
            }
        }
#pragma unroll
        for (int h = 0; h < HPL; ++h) {
            half8_t o;
#pragma unroll
            for (int j = 0; j < 8; ++j) {
                int ch = l8 * (HPL * 8) + h * 8 + j;
                o[j] = (_Float16)fmaxf(fmaf(a[h * 8 + j], dd, bias[ch]), 0.f);
            }
            *(half8_t*)(sX + ln * XS + l8 * (HPL * 8) + h * 8) = o;
        }
    } else {
#pragma unroll
        for (int h = 0; h < HPL; ++h)
            *(half8_t*)(sX + ln * XS + l8 * (HPL * 8) + h * 8) =
                (half8_t){(_Float16)0.f, (_Float16)0.f, (_Float16)0.f, (_Float16)0.f,
                          (_Float16)0.f, (_Float16)0.f, (_Float16)0.f, (_Float16)0.f};
    }
    __syncthreads();

    // ---- phase B ----
    constexpr int CWV = DOUT / 16;          // 4 (DOUT=64) or 2 (DOUT=32)
    constexpr int MT  = (CWV == 4) ? 2 : 1;
    constexpr int KT  = DIN / 32;
    const int L    = tid & 63;
    const int w    = tid >> 6;
    const int quad = L >> 4;
    const int lm   = L & 15;
    const int c0   = (CWV == 4) ? (w * 16) : ((w & 1) * 16);
    const int m0   = (CWV == 4) ? 0 : ((w >> 1) * 16);

    float4_t acc[MT];
#pragma unroll
    for (int mt = 0; mt < MT; ++mt) acc[mt] = (float4_t){0.f, 0.f, 0.f, 0.f};

#pragma unroll
    for (int kt = 0; kt < KT; ++kt) {
        half8_t b = *(const half8_t*)(WT + (size_t)(c0 + lm) * DIN + kt * 32 + quad * 8);
#pragma unroll
        for (int mt = 0; mt < MT; ++mt) {
            half8_t aF = *(const half8_t*)(sX + (m0 + mt * 16 + lm) * XS + kt * 32 + quad * 8);
            acc[mt] = __builtin_amdgcn_mfma_f32_16x16x32_f16(aF, b, acc[mt], 0, 0, 0);
        }
    }
#pragma unroll
    for (int mt = 0; mt < MT; ++mt) {
        int rb = r0 + m0 + mt * 16 + quad * 4;
        float dv[4];
        *(float4*)dv = *(const float4*)(dis + rb);
#pragma unroll
        for (int reg = 0; reg < 4; ++reg) {
            int r = rb + reg;
            if (r < n)       gout[(size_t)r * DOUT + c0 + lm] = (_Float16)(acc[mt][reg] * dv[reg]);
            else if (r == n) gout[(size_t)r * DOUT + c0 + lm] = (_Float16)0.f;
        }
    }
}

// ---------------- conv2 aggregate (32ch) fused with MLP head ----------------
__global__ __launch_bounds__(256) void k_agg_mlp(const half8_t* __restrict__ g,
        const float* __restrict__ dis, const float* __restrict__ b,
        const int* __restrict__ off, const unsigned short* __restrict__ csr,
        const float* __restrict__ lw0, const float* __restrict__ lb0,
        const float* __restrict__ lw1, const float* __restrict__ lb1,
        const float* __restrict__ lw2, const float* __restrict__ lb2,
        float* __restrict__ sv, int n) {
    __shared__ float sh[32 * 33];
    const int tid  = threadIdx.x;
    const int l8   = tid & 7;
    const int lane = l8 & 3;
    const int grp  = l8 >> 2;
    const int ln   = tid >> 3;               // 32 nodes per block
    const int node = blockIdx.x * 32 + ln;

    if (node < n) {
        float dd = dis[node];
        half8_t hv = g[(size_t)node * 4 + lane];
        float a[8];
#pragma unroll
        for (int j = 0; j < 8; ++j) a[j] = (grp == 0) ? (float)hv[j] : 0.f;
        int pk = off[node];
        int e0 = pk & 0xFFFFF;
        int e1 = e0 + (pk >> 20);
        for (int e = e0 + grp * 4; e < e1; e += 8) {
            ushort4 c4 = *(const ushort4*)(csr + e);
            half8_t v0 = g[(size_t)c4.x * 4 + lane];
            half8_t v1 = g[(size_t)c4.y * 4 + lane];
            half8_t v2 = g[(size_t)c4.z * 4 + lane];
            half8_t v3 = g[(size_t)c4.w * 4 + lane];
#pragma unroll
            for (int j = 0; j < 8; ++j)
                a[j] += (float)v0[j] + (float)v1[j] + (float)v2[j] + (float)v3[j];
        }
#pragma unroll
        for (int j = 0; j < 8; ++j) a[j] += __shfl_xor(a[j], 4);
        if (grp == 0) {
            float* row = sh + ln * 33 + lane * 8;
#pragma unroll
            for (int j = 0; j < 8; ++j)
                row[j] = fmaxf(fmaf(a[j], dd, b[lane * 8 + j]), 0.f);
        }
    }
    __syncthreads();

    if (tid < 32) {
        int node2 = blockIdx.x * 32 + tid;
        if (node2 < n) {
            const float* v = sh + tid * 33;
            float a[16];
#pragma unroll
            for (int j = 0; j < 16; ++j) {
                float acc = lb0[j];
#pragma unroll
                for (int k = 0; k < 32; ++k) acc = fmaf(v[k], lw0[k * 16 + j], acc);
                a[j] = fmaxf(acc, 0.f);
            }
            float b8[8];
#pragma unroll
            for (int j = 0; j < 8; ++j) {
                float acc = lb1[j];
#pragma unroll
                for (int k = 0; k < 16; ++k) acc = fmaf(a[k], lw1[k * 8 + j], acc);
                b8[j] = fmaxf(acc, 0.f);
            }
            float z = lb2[0];
#pragma unroll
            for (int k = 0; k < 8; ++k) z = fmaf(b8[k], lw2[k], z);
            sv[node2] = 1.0f / (1.0f + expf(-z));
        }
    }
}

// ---------------- link prediction: 2 edges per thread ----------------
__global__ void k_pred(const float* __restrict__ s, const int* __restrict__ pe,
                       float* __restrict__ out, int ep2) {
    int i = blockIdx.x * blockDim.x + threadIdx.x;
    if (i >= ep2) return;
    int4 p = ((const int4*)pe)[i];
    float2 o;
    o.x = s[p.x] * s[p.y];
    o.y = s[p.z] * s[p.w];
    ((float2*)out)[i] = o;
}

extern "C" void kernel_launch(void* const* d_in, const int* in_sizes, int n_in,
                              void* d_out, int out_size, void* d_ws, size_t ws_size,
                              hipStream_t stream) {
    const float* x   = (const float*)d_in[0];
    const int*   ei  = (const int*)d_in[1];
    const int*   pe  = (const int*)d_in[2];
    const float* cw0 = (const float*)d_in[3];
    const float* cb0 = (const float*)d_in[4];
    const float* cw1 = (const float*)d_in[5];
    const float* cb1 = (const float*)d_in[6];
    const float* cw2 = (const float*)d_in[7];
    const float* cb2 = (const float*)d_in[8];
    const float* lw0 = (const float*)d_in[9];
    const float* lb0 = (const float*)d_in[10];
    const float* lw1 = (const float*)d_in[11];
    const float* lb1 = (const float*)d_in[12];
    const float* lw2 = (const float*)d_in[13];
    const float* lb2 = (const float*)d_in[14];

    const int* src = ei;        // edge_index[0]
    const int* dst = ei + NE;   // edge_index[1]

    // workspace layout
    char* w = (char*)d_ws;
    float*          dis  = (float*)w;           w += sizeof(float) * NN;
    _Float16*       M0   = (_Float16*)w;        w += sizeof(_Float16) * (size_t)(NN + 1) * 128;
    _Float16*       M1   = (_Float16*)w;        w += sizeof(_Float16) * (size_t)(NN + 1) * 64;
    _Float16*       M2   = (_Float16*)w;        w += sizeof(_Float16) * (size_t)(NN + 1) * 32;
    float*          sv   = (float*)w;           w += sizeof(float) * NN;
    _Float16*       WT0  = (_Float16*)w;        w += sizeof(_Float16) * 128 * 128;
    _Float16*       WT1  = (_Float16*)w;        w += sizeof(_Float16) * 64 * 128;
    _Float16*       WT2  = (_Float16*)w;        w += sizeof(_Float16) * 32 * 64;
    int*            off  = (int*)w;             w += sizeof(int) * NN;
    unsigned short* csr  = (unsigned short*)w;  w += sizeof(unsigned short) * (size_t)NBKT * CAPC;
    int*            binCnt = (int*)w;           w += sizeof(int) * NBKT;
    unsigned int*   ebuf = (unsigned int*)w;    w += sizeof(unsigned int) * (size_t)NBKT * CAP;

    const int T = 256;

    // --- front end: bucket + weight transposes ---
    hipMemsetAsync(binCnt, 0, sizeof(int) * NBKT, stream);
    k_front<<<FRONT_BLOCKS, 256, 0, stream>>>(src, dst, binCnt, ebuf,
                                              cw0, WT0, cw1, WT1, cw2, WT2);

    // --- CSR build (padded segments, per-bin regions) ---
    k_csrbuild<<<NBKT, 256, 0, stream>>>(ebuf, binCnt, off, dis, csr);

    // --- conv0 GEMM: x (fp32) -> msg0 ---
    k_gemm0<<<NP / 64, 256, 0, stream>>>(x, WT0, dis, M0, NN);

    // --- conv0 aggregate + conv1 GEMM fused: msg0 -> msg1 ---
    k_agg_gemm<128, 64><<<NODE_BLKS32, 256, 0, stream>>>((const half8_t*)M0, dis, cb0,
                                                         off, csr, WT1, M1, NN);

    // --- conv1 aggregate + conv2 GEMM fused: msg1 -> msg2 ---
    k_agg_gemm<64, 32><<<NODE_BLKS32, 256, 0, stream>>>((const half8_t*)M1, dis, cb1,
                                                        off, csr, WT2, M2, NN);

    // --- conv2 aggregate + MLP head: msg2 -> sv ---
    k_agg_mlp<<<NODE_BLKS32, 256, 0, stream>>>((const half8_t*)M2, dis, cb2, off, csr,
                                               lw0, lb0, lw1, lb1, lw2, lb2, sv, NN);

    // --- link prediction ---
    k_pred<<<cdiv(NEP / 2, T), T, 0, stream>>>(sv, pe, (float*)d_out, NEP / 2);
}

// Round 13
// 213.219 us; speedup vs baseline: 1.1941x; 1.0216x over previous
//
#include <hip/hip_runtime.h>
#include <math.h>

constexpr int NN  = 50000;   // nodes (< 65536 -> csr fits in ushort)
constexpr int NP  = 50048;   // padded rows (multiple of 128)
constexpr int NE  = 800000;  // edges
constexpr int NEP = 200000;  // pred edges

// CSR-build binning
constexpr int NBKT  = 256;   // bins; bin = dst >> 8
constexpr int CAP   = 4096;  // per-bin ebuf capacity
constexpr int CAPC  = 4096;  // per-bin csr region
constexpr int CHUNK = 4096;  // edges per bucket workgroup

constexpr int BKB = (NE + CHUNK - 1) / CHUNK;          // 196 bucket blocks
constexpr int W0B = 128 * 128 / 256;                   // 64
constexpr int W1B = 128 * 64 / 256;                    // 32
constexpr int W2B = 64 * 32 / 256;                     // 8
constexpr int FRONT_BLOCKS = BKB + W0B + W1B + W2B;

constexpr int NODE_BLKS32 = (NN + 31) / 32;            // 1563 blocks @ 32 nodes
constexpr int NODE_BLKS16 = (NN + 15) / 16;            // 3125 blocks @ 16 nodes (exact)

typedef _Float16 half8_t __attribute__((ext_vector_type(8)));
typedef float    float4_t __attribute__((ext_vector_type(4)));

static inline int cdiv(long long a, int b) { return (int)((a + b - 1) / b); }

// ---------------- fused front end: bucket edges + W transposes ----------------
__global__ __launch_bounds__(256) void k_front(const int* __restrict__ src,
        const int* __restrict__ dst, int* __restrict__ binCnt,
        unsigned int* __restrict__ ebuf,
        const float* __restrict__ cw0, _Float16* __restrict__ WT0,
        const float* __restrict__ cw1, _Float16* __restrict__ WT1,
        const float* __restrict__ cw2, _Float16* __restrict__ WT2) {
    const int tid = threadIdx.x;
    const int bid = blockIdx.x;

    if (bid < BKB) {
        __shared__ int hist[NBKT];
        __shared__ int base[NBKT];
        __shared__ int cur[NBKT];
        constexpr int J = CHUNK / 256;   // 16 edges per thread
        const int e0 = bid * CHUNK;
        hist[tid] = 0;
        __syncthreads();
        int  s[J], bn[J], dl[J];
        bool ok[J];
#pragma unroll
        for (int j = 0; j < J; ++j) {
            int i = e0 + j * 256 + tid;
            ok[j] = i < NE;
            if (ok[j]) {
                int d = dst[i];
                s[j]  = src[i];
                bn[j] = d >> 8;
                dl[j] = d & 255;
                atomicAdd(&hist[bn[j]], 1);
            }
        }
        __syncthreads();
        base[tid] = hist[tid] ? atomicAdd(&binCnt[tid], hist[tid]) : 0;
        cur[tid] = 0;
        __syncthreads();
#pragma unroll
        for (int j = 0; j < J; ++j) {
            if (ok[j]) {
                int slot = base[bn[j]] + atomicAdd(&cur[bn[j]], 1);
                ebuf[bn[j] * CAP + slot] = (unsigned int)s[j] | ((unsigned int)dl[j] << 16);
            }
        }
        return;
    }
    if (bid < BKB + W0B) {
        int idx = (bid - BKB) * 256 + tid;
        int k = idx >> 7, n = idx & 127;            // K=128, N=128
        WT0[(size_t)n * 128 + k] = (_Float16)cw0[idx];
        return;
    }
    if (bid < BKB + W0B + W1B) {
        int idx = (bid - BKB - W0B) * 256 + tid;
        int k = idx >> 6, n = idx & 63;             // K=128, N=64
        WT1[(size_t)n * 128 + k] = (_Float16)cw1[idx];
        return;
    }
    {
        int idx = (bid - BKB - W0B - W1B) * 256 + tid;
        int k = idx >> 5, n = idx & 31;             // K=64, N=32
        WT2[(size_t)n * 64 + k] = (_Float16)cw2[idx];
    }
}

// ---------------- CSR build: per-bin fixed region, segments padded to x4 ----------------
// off[node] = start | (paddedCnt << 20); pads point at zero-row index NN.
__global__ __launch_bounds__(256) void k_csrbuild(const unsigned int* __restrict__ ebuf,
        const int* __restrict__ binCnt, int* __restrict__ off, float* __restrict__ dis,
        unsigned short* __restrict__ csr) {
    __shared__ int hist[256];
    __shared__ int sh[256];
    __shared__ int cur[256];
    const int tid = threadIdx.x;
    const int bin = blockIdx.x;
    const int cnt = binCnt[bin];
    const unsigned int* eb = ebuf + (size_t)bin * CAP;

    hist[tid] = 0;
    __syncthreads();
    for (int i = tid; i < cnt; i += 256)
        atomicAdd(&hist[eb[i] >> 16], 1);
    __syncthreads();

    int v  = hist[tid];
    int pv = (v + 3) & ~3;
    sh[tid] = pv;
    __syncthreads();
    for (int d = 1; d < 256; d <<= 1) {
        int t = (tid >= d) ? sh[tid - d] : 0;
        __syncthreads();
        sh[tid] += t;
        __syncthreads();
    }
    int start = bin * CAPC + (sh[tid] - pv);

    int node = bin * 256 + tid;
    if (node < NN) {
        off[node] = start | (pv << 20);
        dis[node] = rsqrtf((float)v + 1.0f);
    }
    cur[tid] = start;
    __syncthreads();

    for (int i = tid; i < cnt; i += 256) {
        unsigned int e = eb[i];
        int p = atomicAdd(&cur[e >> 16], 1);
        csr[p] = (unsigned short)(e & 0xFFFFu);
    }
    for (int k2 = v; k2 < pv; ++k2) csr[start + k2] = (unsigned short)NN;
}

// ---------------- MFMA GEMM (conv0): msg0 = dis * (x_fp32 @ WT0^T) ----------------
// Output (n+1) x 128 fp16; row n zeroed (pad target).
__global__ __launch_bounds__(256) void k_gemm0(const float* __restrict__ X,
        const _Float16* __restrict__ WT, const float* __restrict__ dis,
        _Float16* __restrict__ g, int n) {
    constexpr int K = 128, DOUT = 128;
    constexpr int NC = 64, NT = 4, KT = 4, MT = 2;

    const int tid  = threadIdx.x;
    const int L    = tid & 63;
    const int w    = tid >> 6;
    const int wc   = w & 1;
    const int wr   = w >> 1;
    const int r0   = blockIdx.x * 64 + wr * 32;
    const int c0   = wc * NC;
    const int quad = L >> 4;
    const int lm   = L & 15;

    float4_t acc[MT][NT];
#pragma unroll
    for (int mt = 0; mt < MT; ++mt)
#pragma unroll
        for (int nt = 0; nt < NT; ++nt) acc[mt][nt] = (float4_t){0.f, 0.f, 0.f, 0.f};

#pragma unroll
    for (int kt = 0; kt < KT; ++kt) {
        half8_t a[MT], b[NT];
#pragma unroll
        for (int mt = 0; mt < MT; ++mt) {
            const float* xr = X + (size_t)(r0 + mt * 16 + lm) * K + kt * 32 + quad * 8;
            float4 u = *(const float4*)xr;
            float4 v = *(const float4*)(xr + 4);
            a[mt] = (half8_t){(_Float16)u.x, (_Float16)u.y, (_Float16)u.z, (_Float16)u.w,
                              (_Float16)v.x, (_Float16)v.y, (_Float16)v.z, (_Float16)v.w};
        }
#pragma unroll
        for (int nt = 0; nt < NT; ++nt)
            b[nt] = *(const half8_t*)(WT + (size_t)(c0 + nt * 16 + lm) * K + kt * 32 + quad * 8);
#pragma unroll
        for (int mt = 0; mt < MT; ++mt)
#pragma unroll
            for (int nt = 0; nt < NT; ++nt)
                acc[mt][nt] = __builtin_amdgcn_mfma_f32_16x16x32_f16(a[mt], b[nt], acc[mt][nt], 0, 0, 0);
    }

#pragma unroll
    for (int mt = 0; mt < MT; ++mt) {
        int rb = r0 + mt * 16 + quad * 4;
        float dv[4];
        *(float4*)dv = *(const float4*)(dis + rb);
#pragma unroll
        for (int nt = 0; nt < NT; ++nt) {
            int c = c0 + nt * 16 + lm;
#pragma unroll
            for (int reg = 0; reg < 4; ++reg) {
                int r = rb + reg;
                if (r < n)       g[(size_t)r * DOUT + c] = (_Float16)(acc[mt][nt][reg] * dv[reg]);
                else if (r == n) g[(size_t)r * DOUT + c] = (_Float16)0.f;
            }
        }
    }
}

// ---------------- fused conv0-aggregate + conv1-GEMM: 16 lanes/node ----------------
// Phase A: 16 nodes/block, 16 lanes/node aggregate 128 ch (1 half8 load per row),
//          edge loop unrolled x2 (8 rows in flight). relu(dis*acc+b) -> LDS fp16.
// Phase B: 16 x 64 MFMA from LDS vs WT1; prescaled fp16 messages -> gout.
__global__ __launch_bounds__(256) void k_agg_gemm16(const half8_t* __restrict__ gin,
        const float* __restrict__ dis, const float* __restrict__ bias,
        const int* __restrict__ off, const unsigned short* __restrict__ csr,
        const _Float16* __restrict__ WT, _Float16* __restrict__ gout, int n) {
    constexpr int DIN = 128, DOUT = 64;
    constexpr int R8 = DIN / 8;         // 16 half8 per input row
    constexpr int XS = DIN + 8;         // padded LDS row stride (fp16)
    __shared__ _Float16 sX[16 * XS];

    const int tid  = threadIdx.x;
    const int l16  = tid & 15;
    const int ln   = tid >> 4;          // local node 0..15
    const int r0   = blockIdx.x * 16;
    const int node = r0 + ln;           // always < n (3125*16 == 50000)

    // zero the pad row of gout (read by next layer's csr pads)
    if (blockIdx.x == 0 && tid < DOUT / 8)
        ((half8_t*)(gout + (size_t)n * DOUT))[tid] =
            (half8_t){(_Float16)0.f, (_Float16)0.f, (_Float16)0.f, (_Float16)0.f,
                      (_Float16)0.f, (_Float16)0.f, (_Float16)0.f, (_Float16)0.f};

    // ---- phase A: aggregate ----
    float dd = dis[node];
    half8_t hv = gin[(size_t)node * R8 + l16];
    float a[8];
#pragma unroll
    for (int j = 0; j < 8; ++j) a[j] = (float)hv[j];

    int pk = off[node];
    int e0 = pk & 0xFFFFF;
    int e1 = e0 + (pk >> 20);
    int e = e0;
    for (; e + 7 < e1; e += 8) {
        ushort4 c4 = *(const ushort4*)(csr + e);
        ushort4 c8 = *(const ushort4*)(csr + e + 4);
        half8_t v0 = gin[(size_t)c4.x * R8 + l16];
        half8_t v1 = gin[(size_t)c4.y * R8 + l16];
        half8_t v2 = gin[(size_t)c4.z * R8 + l16];
        half8_t v3 = gin[(size_t)c4.w * R8 + l16];
        half8_t v4 = gin[(size_t)c8.x * R8 + l16];
        half8_t v5 = gin[(size_t)c8.y * R8 + l16];
        half8_t v6 = gin[(size_t)c8.z * R8 + l16];
        half8_t v7 = gin[(size_t)c8.w * R8 + l16];
#pragma unroll
        for (int j = 0; j < 8; ++j)
            a[j] += ((float)v0[j] + (float)v1[j]) + ((float)v2[j] + (float)v3[j])
                  + ((float)v4[j] + (float)v5[j]) + ((float)v6[j] + (float)v7[j]);
    }
    if (e < e1) {   // padded counts are multiples of 4 -> remainder is exactly 4
        ushort4 c4 = *(const ushort4*)(csr + e);
        half8_t v0 = gin[(size_t)c4.x * R8 + l16];
        half8_t v1 = gin[(size_t)c4.y * R8 + l16];
        half8_t v2 = gin[(size_t)c4.z * R8 + l16];
        half8_t v3 = gin[(size_t)c4.w * R8 + l16];
#pragma unroll
        for (int j = 0; j < 8; ++j)
            a[j] += ((float)v0[j] + (float)v1[j]) + ((float)v2[j] + (float)v3[j]);
    }
    {
        half8_t o;
#pragma unroll
        for (int j = 0; j < 8; ++j)
            o[j] = (_Float16)fmaxf(fmaf(a[j], dd, bias[l16 * 8 + j]), 0.f);
        *(half8_t*)(sX + ln * XS + l16 * 8) = o;
    }
    __syncthreads();

    // ---- phase B: 16 x 64 MFMA (4 waves x 16 cols) ----
    const int L    = tid & 63;
    const int w    = tid >> 6;
    const int quad = L >> 4;
    const int lm   = L & 15;
    const int c0   = w * 16;

    float4_t acc = (float4_t){0.f, 0.f, 0.f, 0.f};
#pragma unroll
    for (int kt = 0; kt < DIN / 32; ++kt) {
        half8_t b  = *(const half8_t*)(WT + (size_t)(c0 + lm) * DIN + kt * 32 + quad * 8);
        half8_t aF = *(const half8_t*)(sX + lm * XS + kt * 32 + quad * 8);
        acc = __builtin_amdgcn_mfma_f32_16x16x32_f16(aF, b, acc, 0, 0, 0);
    }
    int rb = r0 + quad * 4;
    float dv[4];
    *(float4*)dv = *(const float4*)(dis + rb);
#pragma unroll
    for (int reg = 0; reg < 4; ++reg)
        gout[(size_t)(rb + reg) * DOUT + c0 + lm] = (_Float16)(acc[reg] * dv[reg]);
}

// ---------------- fused conv1-aggregate + conv2-GEMM: 8 lanes/node, unroll x2 ----------------
__global__ __launch_bounds__(256) void k_agg_gemm8(const half8_t* __restrict__ gin,
        const float* __restrict__ dis, const float* __restrict__ bias,
        const int* __restrict__ off, const unsigned short* __restrict__ csr,
        const _Float16* __restrict__ WT, _Float16* __restrict__ gout, int n) {
    constexpr int DIN = 64, DOUT = 32;
    constexpr int R8 = DIN / 8;         // 8 half8 per input row
    constexpr int XS = DIN + 8;         // 72
    __shared__ _Float16 sX[32 * XS];

    const int tid  = threadIdx.x;
    const int l8   = tid & 7;
    const int ln   = tid >> 3;          // local node 0..31
    const int r0   = blockIdx.x * 32;
    const int node = r0 + ln;

    // ---- phase A ----
    if (node < n) {
        float dd = dis[node];
        half8_t hv = gin[(size_t)node * R8 + l8];
        float a[8];
#pragma unroll
        for (int j = 0; j < 8; ++j) a[j] = (float)hv[j];
        int pk = off[node];
        int e0 = pk & 0xFFFFF;
        int e1 = e0 + (pk >> 20);
        int e = e0;
        for (; e + 7 < e1; e += 8) {
            ushort4 c4 = *(const ushort4*)(csr + e);
            ushort4 c8 = *(const ushort4*)(csr + e + 4);
            half8_t v0 = gin[(size_t)c4.x * R8 + l8];
            half8_t v1 = gin[(size_t)c4.y * R8 + l8];
            half8_t v2 = gin[(size_t)c4.z * R8 + l8];
            half8_t v3 = gin[(size_t)c4.w * R8 + l8];
            half8_t v4 = gin[(size_t)c8.x * R8 + l8];
            half8_t v5 = gin[(size_t)c8.y * R8 + l8];
            half8_t v6 = gin[(size_t)c8.z * R8 + l8];
            half8_t v7 = gin[(size_t)c8.w * R8 + l8];
#pragma unroll
            for (int j = 0; j < 8; ++j)
                a[j] += ((float)v0[j] + (float)v1[j]) + ((float)v2[j] + (float)v3[j])
                      + ((float)v4[j] + (float)v5[j]) + ((float)v6[j] + (float)v7[j]);
        }
        if (e < e1) {
            ushort4 c4 = *(const ushort4*)(csr + e);
            half8_t v0 = gin[(size_t)c4.x * R8 + l8];
            half8_t v1 = gin[(size_t)c4.y * R8 + l8];
            half8_t v2 = gin[(size_t)c4.z * R8 + l8];
            half8_t v3 = gin[(size_t)c4.w * R8 + l8];
#pragma unroll
            for (int j = 0; j < 8; ++j)
                a[j] += ((float)v0[j] + (float)v1[j]) + ((float)v2[j] + (float)v3[j]);
        }
        half8_t o;
#pragma unroll
        for (int j = 0; j < 8; ++j)
            o[j] = (_Float16)fmaxf(fmaf(a[j], dd, bias[l8 * 8 + j]), 0.f);
        *(half8_t*)(sX + ln * XS + l8 * 8) = o;
    } else {
        *(half8_t*)(sX + ln * XS + l8 * 8) =
            (half8_t){(_Float16)0.f, (_Float16)0.f, (_Float16)0.f, (_Float16)0.f,
                      (_Float16)0.f, (_Float16)0.f, (_Float16)0.f, (_Float16)0.f};
    }
    __syncthreads();

    // ---- phase B: 32 x 32 MFMA (2 col groups x 2 row halves) ----
    const int L    = tid & 63;
    const int w    = tid >> 6;
    const int quad = L >> 4;
    const int lm   = L & 15;
    const int c0   = (w & 1) * 16;
    const int m0   = (w >> 1) * 16;

    float4_t acc = (float4_t){0.f, 0.f, 0.f, 0.f};
#pragma unroll
    for (int kt = 0; kt < DIN / 32; ++kt) {
        half8_t b  = *(const half8_t*)(WT + (size_t)(c0 + lm) * DIN + kt * 32 + quad * 8);
        half8_t aF = *(const half8_t*)(sX + (m0 + lm) * XS + kt * 32 + quad * 8);
        acc = __builtin_amdgcn_mfma_f32_16x16x32_f16(aF, b, acc, 0, 0, 0);
    }
    int rb = r0 + m0 + quad * 4;
    float dv[4];
    *(float4*)dv = *(const float4*)(dis + rb);
#pragma unroll
    for (int reg = 0; reg < 4; ++reg) {
        int r = rb + reg;
        if (r < n)       gout[(size_t)r * DOUT + c0 + lm] = (_Float16)(acc[reg] * dv[reg]);
        else if (r == n) gout[(size_t)r * DOUT + c0 + lm] = (_Float16)0.f;
    }
}

// ---------------- conv2 aggregate (32ch) fused with MLP head ----------------
__global__ __launch_bounds__(256) void k_agg_mlp(const half8_t* __restrict__ g,
        const float* __restrict__ dis, const float* __restrict__ b,
        const int* __restrict__ off, const unsigned short* __restrict__ csr,
        const float* __restrict__ lw0, const float* __restrict__ lb0,
        const float* __restrict__ lw1, const float* __restrict__ lb1,
        const float* __restrict__ lw2, const float* __restrict__ lb2,
        float* __restrict__ sv, int n) {
    __shared__ float sh[32 * 33];
    const int tid  = threadIdx.x;
    const int l8   = tid & 7;
    const int lane = l8 & 3;
    const int grp  = l8 >> 2;
    const int ln   = tid >> 3;               // 32 nodes per block
    const int node = blockIdx.x * 32 + ln;

    if (node < n) {
        float dd = dis[node];
        half8_t hv = g[(size_t)node * 4 + lane];
        float a[8];
#pragma unroll
        for (int j = 0; j < 8; ++j) a[j] = (grp == 0) ? (float)hv[j] : 0.f;
        int pk = off[node];
        int e0 = pk & 0xFFFFF;
        int e1 = e0 + (pk >> 20);
        for (int e = e0 + grp * 4; e < e1; e += 8) {
            ushort4 c4 = *(const ushort4*)(csr + e);
            half8_t v0 = g[(size_t)c4.x * 4 + lane];
            half8_t v1 = g[(size_t)c4.y * 4 + lane];
            half8_t v2 = g[(size_t)c4.z * 4 + lane];
            half8_t v3 = g[(size_t)c4.w * 4 + lane];
#pragma unroll
            for (int j = 0; j < 8; ++j)
                a[j] += (float)v0[j] + (float)v1[j] + (float)v2[j] + (float)v3[j];
        }
#pragma unroll
        for (int j = 0; j < 8; ++j) a[j] += __shfl_xor(a[j], 4);
        if (grp == 0) {
            float* row = sh + ln * 33 + lane * 8;
#pragma unroll
            for (int j = 0; j < 8; ++j)
                row[j] = fmaxf(fmaf(a[j], dd, b[lane * 8 + j]), 0.f);
        }
    }
    __syncthreads();

    if (tid < 32) {
        int node2 = blockIdx.x * 32 + tid;
        if (node2 < n) {
            const float* v = sh + tid * 33;
            float a[16];
#pragma unroll
            for (int j = 0; j < 16; ++j) {
                float acc = lb0[j];
#pragma unroll
                for (int k = 0; k < 32; ++k) acc = fmaf(v[k], lw0[k * 16 + j], acc);
                a[j] = fmaxf(acc, 0.f);
            }
            float b8[8];
#pragma unroll
            for (int j = 0; j < 8; ++j) {
                float acc = lb1[j];
#pragma unroll
                for (int k = 0; k < 16; ++k) acc = fmaf(a[k], lw1[k * 8 + j], acc);
                b8[j] = fmaxf(acc, 0.f);
            }
            float z = lb2[0];
#pragma unroll
            for (int k = 0; k < 8; ++k) z = fmaf(b8[k], lw2[k], z);
            sv[node2] = 1.0f / (1.0f + expf(-z));
        }
    }
}

// ---------------- link prediction: 2 edges per thread ----------------
__global__ void k_pred(const float* __restrict__ s, const int* __restrict__ pe,
                       float* __restrict__ out, int ep2) {
    int i = blockIdx.x * blockDim.x + threadIdx.x;
    if (i >= ep2) return;
    int4 p = ((const int4*)pe)[i];
    float2 o;
    o.x = s[p.x] * s[p.y];
    o.y = s[p.z] * s[p.w];
    ((float2*)out)[i] = o;
}

extern "C" void kernel_launch(void* const* d_in, const int* in_sizes, int n_in,
                              void* d_out, int out_size, void* d_ws, size_t ws_size,
                              hipStream_t stream) {
    const float* x   = (const float*)d_in[0];
    const int*   ei  = (const int*)d_in[1];
    const int*   pe  = (const int*)d_in[2];
    const float* cw0 = (const float*)d_in[3];
    const float* cb0 = (const float*)d_in[4];
    const float* cw1 = (const float*)d_in[5];
    const float* cb1 = (const float*)d_in[6];
    const float* cw2 = (const float*)d_in[7];
    const float* cb2 = (const float*)d_in[8];
    const float* lw0 = (const float*)d_in[9];
    const float* lb0 = (const float*)d_in[10];
    const float* lw1 = (const float*)d_in[11];
    const float* lb1 = (const float*)d_in[12];
    const float* lw2 = (const float*)d_in[13];
    const float* lb2 = (const float*)d_in[14];

    const int* src = ei;        // edge_index[0]
    const int* dst = ei + NE;   // edge_index[1]

    // workspace layout
    char* w = (char*)d_ws;
    float*          dis  = (float*)w;           w += sizeof(float) * NN;
    _Float16*       M0   = (_Float16*)w;        w += sizeof(_Float16) * (size_t)(NN + 1) * 128;
    _Float16*       M1   = (_Float16*)w;        w += sizeof(_Float16) * (size_t)(NN + 1) * 64;
    _Float16*       M2   = (_Float16*)w;        w += sizeof(_Float16) * (size_t)(NN + 1) * 32;
    float*          sv   = (float*)w;           w += sizeof(float) * NN;
    _Float16*       WT0  = (_Float16*)w;        w += sizeof(_Float16) * 128 * 128;
    _Float16*       WT1  = (_Float16*)w;        w += sizeof(_Float16) * 64 * 128;
    _Float16*       WT2  = (_Float16*)w;        w += sizeof(_Float16) * 32 * 64;
    int*            off  = (int*)w;             w += sizeof(int) * NN;
    unsigned short* csr  = (unsigned short*)w;  w += sizeof(unsigned short) * (size_t)NBKT * CAPC;
    int*            binCnt = (int*)w;           w += sizeof(int) * NBKT;
    unsigned int*   ebuf = (unsigned int*)w;    w += sizeof(unsigned int) * (size_t)NBKT * CAP;

    const int T = 256;

    // --- front end: bucket + weight transposes ---
    hipMemsetAsync(binCnt, 0, sizeof(int) * NBKT, stream);
    k_front<<<FRONT_BLOCKS, 256, 0, stream>>>(src, dst, binCnt, ebuf,
                                              cw0, WT0, cw1, WT1, cw2, WT2);

    // --- CSR build (padded segments, per-bin regions) ---
    k_csrbuild<<<NBKT, 256, 0, stream>>>(ebuf, binCnt, off, dis, csr);

    // --- conv0 GEMM: x (fp32) -> msg0 ---
    k_gemm0<<<NP / 64, 256, 0, stream>>>(x, WT0, dis, M0, NN);

    // --- conv0 aggregate + conv1 GEMM fused (16 lanes/node): msg0 -> msg1 ---
    k_agg_gemm16<<<NODE_BLKS16, 256, 0, stream>>>((const half8_t*)M0, dis, cb0,
                                                  off, csr, WT1, M1, NN);

    // --- conv1 aggregate + conv2 GEMM fused (8 lanes/node): msg1 -> msg2 ---
    k_agg_gemm8<<<NODE_BLKS32, 256, 0, stream>>>((const half8_t*)M1, dis, cb1,
                                                 off, csr, WT2, M2, NN);

    // --- conv2 aggregate + MLP head: msg2 -> sv ---
    k_agg_mlp<<<NODE_BLKS32, 256, 0, stream>>>((const half8_t*)M2, dis, cb2, off, csr,
                                               lw0, lb0, lw1, lb1, lw2, lb2, sv, NN);

    // --- link prediction ---
    k_pred<<<cdiv(NEP / 2, T), T, 0, stream>>>(sv, pe, (float*)d_out, NEP / 2);
}